// Round 7
// baseline (299.740 us; speedup 1.0000x reference)
//
#include <hip/hip_runtime.h>
#include <hip/hip_bf16.h>
#include <math.h>

#define D_MODEL 512
#define D_INNER 1024
#define D_STATE 128
#define CONV_DIM (D_INNER + 2*D_STATE)        // 1280
#define D_IN_PROJ (2*D_INNER + 2*D_STATE + 1) // 2305
#define NPROJ 2304                            // z + xBC cols (dt col via GEMV)
#define BATCH 8
#define SEQ 2048
#define NROWS (BATCH*SEQ)                     // 16384
#define CHUNK 128
#define NCHUNK (NROWS/CHUNK)                  // 128 total (16 per batch)
#define CPB (SEQ/CHUNK)                       // 16 chunks per batch
#define EPS_RMS 1e-5f

typedef __hip_bfloat16 bf16;
typedef __attribute__((ext_vector_type(8))) short short8;
typedef __attribute__((ext_vector_type(4))) float f32x4;

__device__ __forceinline__ float fbf(bf16 v) { return __bfloat162float(v); }
__device__ __forceinline__ bf16 tbf(float v) { return __float2bfloat16(v); }
__device__ __forceinline__ float fexp(float x) { return __expf(x); }          // v_exp_f32
__device__ __forceinline__ float frcp(float x) { return __builtin_amdgcn_rcpf(x); }
__device__ __forceinline__ float fsilu(float a) { return a * frcp(1.f + fexp(-a)); }

// async global->LDS, 16B per lane; LDS dest is wave-uniform base + lane*16
__device__ __forceinline__ void gl2lds16(const bf16* g, bf16* l) {
    __builtin_amdgcn_global_load_lds(
        (const __attribute__((address_space(1))) unsigned int*)g,
        (__attribute__((address_space(3))) unsigned int*)l, 16, 0, 0);
}

// ---------- prologue: both weight transposes (+norm_w fold) + rnn tail copy ----------
// 1D grid: [0,1152) = W_in^T tiles, [1152,1664) = W_out^T tiles, 1664 = rnn copy.
__global__ __launch_bounds__(256) void k_prologue(
    const float* __restrict__ W_in, const float* __restrict__ W_out,
    const float* __restrict__ norm_w, const float* __restrict__ rnn,
    bf16* __restrict__ W_inbT, bf16* __restrict__ W_outbT, float* __restrict__ outTail)
{
    int b = blockIdx.x;
    if (b == 1152 + 512) {  // rnn passthrough: 8*512 fp32
        int tid = threadIdx.x;
        #pragma unroll
        for (int i = 0; i < 4; ++i)
            *(float4*)(outTail + (tid + i * 256) * 4) =
                *(const float4*)(rnn + (tid + i * 256) * 4);
        return;
    }
    __shared__ float tile[32][33];
    const float* src; bf16* dst; const float* scale;
    int c0, r0, sstride, C;
    if (b < 1152) {           // W_in[D_MODEL][D_IN_PROJ] -> W_inbT[NPROJ][D_MODEL]
        src = W_in; dst = W_inbT; scale = nullptr;
        c0 = (b % 16) * 32; r0 = (b / 16) * 32; sstride = D_IN_PROJ; C = D_MODEL;
    } else {                  // W_out[D_INNER][D_MODEL] -> W_outbT[D_MODEL][D_INNER], *norm_w
        int bb = b - 1152;
        src = W_out; dst = W_outbT; scale = norm_w;
        c0 = (bb % 32) * 32; r0 = (bb / 32) * 32; sstride = D_MODEL; C = D_INNER;
    }
    int tx = threadIdx.x & 31, ty = threadIdx.x >> 5;
    #pragma unroll
    for (int i = 0; i < 32; i += 8) {
        float s = scale ? scale[c0 + ty + i] : 1.f;
        tile[ty + i][tx] = src[(size_t)(c0 + ty + i) * sstride + (r0 + tx)] * s;
    }
    __syncthreads();
    #pragma unroll
    for (int i = 0; i < 32; i += 8)
        dst[(size_t)(r0 + ty + i) * C + (c0 + tx)] = tbf(tile[tx][ty + i]);
}

// ---------- fused x->bf16 convert + dt GEMV + softplus + ssq zeroing ----------
__global__ __launch_bounds__(256) void k_dtcvt(
    const float* __restrict__ x, const float* __restrict__ W_in,
    const float* __restrict__ dt_bias,
    bf16* __restrict__ xb, float* __restrict__ dts, float* __restrict__ ssq)
{
    __shared__ float wcol[D_MODEL];
    int tid = threadIdx.x;
    wcol[tid]       = W_in[(size_t)tid * D_IN_PROJ + 2304];
    wcol[tid + 256] = W_in[(size_t)(tid + 256) * D_IN_PROJ + 2304];
    __syncthreads();
    int row  = blockIdx.x * 4 + (tid >> 6);
    int lane = tid & 63;
    const float* xr = x + (size_t)row * D_MODEL;
    float4 a = *(const float4*)(xr + lane * 8);
    float4 b = *(const float4*)(xr + lane * 8 + 4);
    union { bf16 o[8]; uint4 u; } pk;
    pk.o[0]=tbf(a.x); pk.o[1]=tbf(a.y); pk.o[2]=tbf(a.z); pk.o[3]=tbf(a.w);
    pk.o[4]=tbf(b.x); pk.o[5]=tbf(b.y); pk.o[6]=tbf(b.z); pk.o[7]=tbf(b.w);
    *(uint4*)(xb + (size_t)row * D_MODEL + lane * 8) = pk.u;
    const float* wc = wcol + lane * 8;
    float s = a.x*wc[0]+a.y*wc[1]+a.z*wc[2]+a.w*wc[3]
            + b.x*wc[4]+b.y*wc[5]+b.z*wc[6]+b.w*wc[7];
    #pragma unroll
    for (int off = 32; off; off >>= 1) s += __shfl_xor(s, off);
    if (lane == 0) {
        float raw = s + dt_bias[0];
        dts[row] = raw > 20.f ? raw : log1pf(fexp(raw));
        ssq[row] = 0.f;
    }
}

// ---------- batched NT GEMM, 128x128 tile, BK=64, LDS double-buffer + counted vmcnt ----------
// (round-2 proven config: 256 thr, 4 waves, 64 KiB LDS -> 2 blocks/CU, vmcnt(8) dist-2)
// MODE 0: fp32 out.  MODE 1: bf16 out.
// MODE 2: Y-epilogue — gate with silu(zg) (zg tile staged to LDS), bf16 out, ssq atomics.
//         (requires bm==0, M==128 per batch index)
// MODE 3: fp32 out scaled by rsqrt(ssq[row]/D_INNER + eps). Grid bm-fastest:
//         the 4 readers of each A-panel are {b,b+128,b+256,b+384} -> same XCD,
//         co-resident -> A fetched once. (bn-fastest swap measured -11 us: do not.)
template<int MODE>
__global__ __launch_bounds__(256) void k_bgemm(
    const bf16* __restrict__ A, int lda, size_t sA,
    const bf16* __restrict__ Bt, int ldb, size_t sB,
    void* __restrict__ Cv, int ldc, size_t sC, int K,
    const bf16* __restrict__ zg, float* __restrict__ ssq)
{
    constexpr int BK = 64;
    __shared__ __align__(16) bf16 SM[4 * 8192];   // As0|Bs0|As1|Bs1 = 64 KiB (2 blocks/CU)
    const int tid = threadIdx.x, lane = tid & 63, wave = tid >> 6;
    const int wm = (wave & 1) * 64, wn = (wave >> 1) * 64;
    const int lr = lane & 15, quad = lane >> 4;
    const int rx = lr & 7;
    const size_t bm = (size_t)blockIdx.x * 128;
    const size_t bn = (size_t)blockIdx.y * 128;
    const size_t bi = blockIdx.z;
    A  += bi * sA;
    Bt += bi * sB;
    const int srow = lane >> 3;
    const int scol = (((lane & 7) ^ srow) << 3);

    f32x4 acc[4][4];
    #pragma unroll
    for (int i = 0; i < 4; ++i)
        #pragma unroll
        for (int j = 0; j < 4; ++j) acc[i][j] = (f32x4){0.f,0.f,0.f,0.f};

    auto stage = [&](bf16* Ad, bf16* Bd, int k0) {
        #pragma unroll
        for (int q = 0; q < 4; ++q) {
            int rg = wave * 32 + q * 8;
            gl2lds16(A  + (bm + rg + srow) * lda + k0 + scol, Ad + rg * BK);
            gl2lds16(Bt + (bn + rg + srow) * ldb + k0 + scol, Bd + rg * BK);
        }
    };

    const int NT = K / BK;
    stage(SM, SM + 8192, 0);                       // tile 0 -> buf0
    if (NT > 1) stage(SM + 16384, SM + 24576, BK); // tile 1 -> buf1

    for (int kt = 0; kt < NT; ++kt) {
        if (kt + 1 < NT) asm volatile("s_waitcnt vmcnt(8)" ::: "memory");
        else             asm volatile("s_waitcnt vmcnt(0)" ::: "memory");
        __builtin_amdgcn_s_barrier();
        __builtin_amdgcn_sched_barrier(0);
        const bf16* As = SM + (kt & 1) * 16384;
        const bf16* Bs = As + 8192;
        #pragma unroll
        for (int ks = 0; ks < BK; ks += 32) {
            const int off = ((((ks >> 3) + quad) ^ rx) << 3);
            short8 af[4], bg[4];
            #pragma unroll
            for (int i = 0; i < 4; ++i)
                af[i] = *(const short8*)(As + (wm + i*16 + lr) * BK + off);
            #pragma unroll
            for (int j = 0; j < 4; ++j)
                bg[j] = *(const short8*)(Bs + (wn + j*16 + lr) * BK + off);
            #pragma unroll
            for (int i = 0; i < 4; ++i)
                #pragma unroll
                for (int j = 0; j < 4; ++j)
                    acc[i][j] = __builtin_amdgcn_mfma_f32_16x16x32_bf16(af[i], bg[j], acc[i][j], 0,0,0);
        }
        __builtin_amdgcn_sched_barrier(0);
        __builtin_amdgcn_s_barrier();
        if (kt + 2 < NT) {
            bf16* An = SM + (kt & 1) * 16384;
            stage(An, An + 8192, (kt + 2) * BK);
        }
    }
    if (MODE <= 1) {
        #pragma unroll
        for (int i = 0; i < 4; ++i)
            #pragma unroll
            for (int j = 0; j < 4; ++j)
                #pragma unroll
                for (int r = 0; r < 4; ++r) {
                    size_t row = bm + wm + i*16 + quad*4 + r;
                    size_t col = bn + wn + j*16 + lr;
                    float v = acc[i][j][r];
                    if (MODE == 0) ((float*)Cv + bi*sC)[row * ldc + col] = v;
                    else           ((bf16*)Cv + bi*sC)[row * ldc + col] = tbf(v);
                }
    } else if (MODE == 2) {
        // stage zg tile (128 rows x 128 cols, XOR-swizzled) into SM, reusing buf0
        const size_t tokbase = bi * CHUNK;
        const bf16* zrow = zg + tokbase * D_INNER + bn;
        __syncthreads();
        #pragma unroll
        for (int q = 0; q < 8; ++q) {
            int r0 = wave * 32 + q * 4;
            int rr = r0 + (lane >> 4);
            int gl = (lane & 15) ^ (rr & 7);
            gl2lds16(zrow + (size_t)rr * D_INNER + gl * 8, SM + r0 * 128);
        }
        __syncthreads();
        float srw[4][4];
        #pragma unroll
        for (int i = 0; i < 4; ++i)
            #pragma unroll
            for (int r = 0; r < 4; ++r) srw[i][r] = 0.f;
        #pragma unroll
        for (int i = 0; i < 4; ++i)
            #pragma unroll
            for (int j = 0; j < 4; ++j)
                #pragma unroll
                for (int r = 0; r < 4; ++r) {
                    int row = wm + i*16 + quad*4 + r;       // 0..127 (bm==0)
                    int col = wn + j*16 + lr;               // 0..127 local
                    int gph = ((col >> 3) ^ (row & 7));
                    float z = fbf(SM[row * 128 + (gph << 3) + (col & 7)]);
                    float g = acc[i][j][r] * z * frcp(1.f + fexp(-z));
                    ((bf16*)Cv + bi*sC)[(size_t)row * ldc + bn + col] = tbf(g);
                    srw[i][r] += g * g;
                }
        #pragma unroll
        for (int i = 0; i < 4; ++i)
            #pragma unroll
            for (int r = 0; r < 4; ++r) {
                float s = srw[i][r];
                s += __shfl_xor(s, 1);
                s += __shfl_xor(s, 2);
                s += __shfl_xor(s, 4);
                s += __shfl_xor(s, 8);
                if (lr == 0)
                    atomicAdd(ssq + tokbase + wm + i*16 + quad*4 + r, s);
            }
    } else {  // MODE 3
        #pragma unroll
        for (int i = 0; i < 4; ++i)
            #pragma unroll
            for (int r = 0; r < 4; ++r) {
                size_t row = bm + wm + i*16 + quad*4 + r;
                float sc = rsqrtf(ssq[row] * (1.f / D_INNER) + EPS_RMS);
                #pragma unroll
                for (int j = 0; j < 4; ++j) {
                    size_t col = bn + wn + j*16 + lr;
                    ((float*)Cv + bi*sC)[row * ldc + col] = acc[i][j][r] * sc;
                }
            }
    }
}

// ---------- GEMM1: 128x128 tile, BK=32, 4-deep LDS pipeline, 2 blocks/CU ----------
// The joint fix for the three isolated constraints: (r5) need >=3 tiles in flight to
// cover ~900cyc HBM latency; (r2/r3) need 2 blocks/CU for barrier-bubble overlap;
// (r3/r4) BK=32's half-cache-line waste becomes L2 hits under the supertile swizzle
// (the other 64B of each 128B line is K-tile kt+1, used one step later).
// 4 buffers x (A 128x32 | B 128x32) x bf16 = 64 KiB -> 2 blocks/CU. 256 threads.
// Ledger: stage = 4 gl2lds/thread. Prologue stages tiles 0..3 -> buf0..3. Iter kt:
// rem=NT-1-kt; wait vmcnt(4*min(rem,3)) -> s_barrier -> compute buf[kt&3] (16 MFMA,
// 8 ds_read_b128/wave) -> s_barrier -> stage tile kt+4 into buf[kt&3]. NT=16.
// BK=32 swizzle (verified r3, 0 conflicts): store col-group g at LDS group
// g^((row>>1)&3); read fragment group quad^((lr>>1)&3).
__global__ __launch_bounds__(256) void k_gemm_in(
    const bf16* __restrict__ A, const bf16* __restrict__ Bt,
    bf16* __restrict__ zb, bf16* __restrict__ xBCin)
{
    constexpr int BK = 32;
    constexpr int K = D_MODEL;
    constexpr int NT = K / BK;                    // 16
    __shared__ __align__(16) bf16 SM[8 * 4096];   // 4 x (A|B) = 64 KiB
    const int tid = threadIdx.x, lane = tid & 63, wave = tid >> 6;
    const int wm = (wave & 1) * 64, wn = (wave >> 1) * 64;
    const int lr = lane & 15, quad = lane >> 4;
    // XCD-chunked supertile swizzle (2304 = 8 XCD * 16 bm * 18 bn, supertile 4bm x 18bn;
    // working set 4 A-panels 0.5MB + 18 B-panels 2.3MB < 4MiB XCD-L2). FETCH 35MB measured (r4).
    const int bid = blockIdx.x;
    const int xcd = bid & 7, lid = bid >> 3;      // lid in [0,288)
    const int st  = lid / 72, r5 = lid % 72;      // 4 supertiles per XCD
    const size_t bm = (size_t)(xcd * 16 + st * 4 + r5 / 18) * 128;
    const int    bn = (r5 % 18) * 128;
    const int srow = lane >> 2;                                   // 16 rows per gl2lds16
    const int scol = (((lane & 3) ^ ((srow >> 1) & 3)) << 3);     // pre-swizzled src group
    const int gread = ((quad ^ ((lr >> 1) & 3)) << 3);            // swizzled frag group

    f32x4 acc[4][4];
    #pragma unroll
    for (int i = 0; i < 4; ++i)
        #pragma unroll
        for (int j = 0; j < 4; ++j) acc[i][j] = (f32x4){0.f,0.f,0.f,0.f};

    auto stage = [&](int buf, int k0) {           // 4 gl2lds per thread
        bf16* Ad = SM + buf * 8192;
        bf16* Bd = Ad + 4096;
        #pragma unroll
        for (int q = 0; q < 2; ++q) {
            int rg = wave * 32 + q * 16;
            gl2lds16(A  + (bm + rg + srow) * K + k0 + scol, Ad + rg * BK);
            gl2lds16(Bt + ((size_t)bn + rg + srow) * K + k0 + scol, Bd + rg * BK);
        }
    };

    stage(0, 0); stage(1, BK); stage(2, 2 * BK); stage(3, 3 * BK);

    for (int kt = 0; kt < NT; ++kt) {
        const int rem = NT - 1 - kt;
        if (rem >= 3)      asm volatile("s_waitcnt vmcnt(12)" ::: "memory");
        else if (rem == 2) asm volatile("s_waitcnt vmcnt(8)"  ::: "memory");
        else if (rem == 1) asm volatile("s_waitcnt vmcnt(4)"  ::: "memory");
        else               asm volatile("s_waitcnt vmcnt(0)"  ::: "memory");
        __builtin_amdgcn_s_barrier();
        __builtin_amdgcn_sched_barrier(0);
        const bf16* As = SM + (kt & 3) * 8192;
        const bf16* Bs = As + 4096;
        short8 af[4], bg[4];
        #pragma unroll
        for (int i = 0; i < 4; ++i)
            af[i] = *(const short8*)(As + (wm + i*16 + lr) * BK + gread);
        #pragma unroll
        for (int j = 0; j < 4; ++j)
            bg[j] = *(const short8*)(Bs + (wn + j*16 + lr) * BK + gread);
        #pragma unroll
        for (int i = 0; i < 4; ++i)
            #pragma unroll
            for (int j = 0; j < 4; ++j)
                acc[i][j] = __builtin_amdgcn_mfma_f32_16x16x32_bf16(af[i], bg[j], acc[i][j], 0,0,0);
        __builtin_amdgcn_sched_barrier(0);
        __builtin_amdgcn_s_barrier();
        if (kt + 4 < NT) stage(kt & 3, (kt + 4) * BK);
    }
    #pragma unroll
    for (int i = 0; i < 4; ++i)
        #pragma unroll
        for (int j = 0; j < 4; ++j)
            #pragma unroll
            for (int r = 0; r < 4; ++r) {
                size_t row = bm + wm + i*16 + quad*4 + r;
                int col = bn + wn + j*16 + lr;
                float v = acc[i][j][r];
                if (col < D_INNER) zb[row * D_INNER + col] = tbf(v);
                else xBCin[row * CONV_DIM + (col - D_INNER)] = tbf(v);
            }
}

// ---------- per-chunk cumsum of a_t = A*dt, decay factors ----------
__global__ void k_prep(const float* __restrict__ dts, const float* __restrict__ A_log,
                       float* __restrict__ svec, float* __restrict__ wvec,
                       float* __restrict__ esvec, float* __restrict__ Pc)
{
    int chunk = blockIdx.x, t = threadIdx.x;  // 128 threads
    int row = chunk * CHUNK + t;
    float A = -fexp(A_log[0]);
    __shared__ float sh[CHUNK];
    sh[t] = A * dts[row];
    __syncthreads();
    for (int off = 1; off < CHUNK; off <<= 1) {
        float v = (t >= off) ? sh[t - off] : 0.f;
        __syncthreads();
        sh[t] += v;
        __syncthreads();
    }
    float s = sh[t], sL = sh[CHUNK - 1];
    svec[row]  = s;
    wvec[row]  = fexp(sL - s) * dts[row];
    esvec[row] = fexp(s);
    if (t == CHUNK - 1) Pc[chunk] = fexp(sL);
}

// ---------- fused conv(B,C) + G = C@B^T + Sm epilogue + Bw/Cs builds ----------
// grid NCHUNK, 256 threads.
__global__ __launch_bounds__(256) void k_ssd_bc(
    const bf16* __restrict__ xBCin, const float* __restrict__ conv_w,
    const float* __restrict__ conv_b, const float* __restrict__ wvec,
    const float* __restrict__ esvec, const float* __restrict__ svec,
    const float* __restrict__ dts, const float* __restrict__ Dp,
    bf16* __restrict__ Bw, bf16* __restrict__ A2)
{
    __shared__ __align__(16) bf16 Ls[131][128];
    __shared__ __align__(16) bf16 Bts[128][136];
    __shared__ __align__(16) bf16 Cts[128][136];
    __shared__ float sv_s[128], dt_s[128], wv_s[128], es_s[128];
    const int chunk = blockIdx.x;
    const int tid = threadIdx.x;
    const bool first = (chunk % CPB) == 0;
    const size_t rowbase = (size_t)chunk * CHUNK;
    if (tid < 128) {
        sv_s[tid] = svec[rowbase + tid];
        dt_s[tid] = dts[rowbase + tid];
        wv_s[tid] = wvec[rowbase + tid];
        es_s[tid] = esvec[rowbase + tid];
    }
    const int ch  = tid & 127;
    const int seg = tid >> 7;   // t-half

    #pragma unroll
    for (int phase = 0; phase < 2; ++phase) {
        const int coff = D_INNER + phase * 128;   // B then C channel base
        __syncthreads();
        for (int i = tid; i < 131 * 16; i += 256) {
            int r = i >> 4, cg = (i & 15) << 3;
            uint4 v = (uint4){0,0,0,0};
            if (!(first && r < 3))
                v = *(const uint4*)(xBCin + (rowbase + r - 3) * CONV_DIM + coff + cg);
            *(uint4*)(&Ls[r][cg]) = v;
        }
        __syncthreads();
        float4 w = *(const float4*)(conv_w + (coff + ch) * 4);
        float bias = conv_b[coff + ch];
        float xv[11];
        #pragma unroll
        for (int i = 0; i < 3; ++i) xv[i + 8] = fbf(Ls[seg * 64 + i][ch]);
        for (int v = 0; v < 8; ++v) {
            int t0 = seg * 64 + v * 8;
            xv[0]=xv[8]; xv[1]=xv[9]; xv[2]=xv[10];
            #pragma unroll
            for (int i = 3; i < 11; ++i) xv[i] = fbf(Ls[t0 + i][ch]);
            float o[8];
            #pragma unroll
            for (int j = 0; j < 8; ++j) {
                float a = bias + w.x*xv[j] + w.y*xv[j+1] + w.z*xv[j+2] + w.w*xv[j+3];
                o[j] = fsilu(a);
            }
            if (phase == 0) {
                union { bf16 ob[8]; uint4 u; } pk;
                #pragma unroll
                for (int j = 0; j < 8; ++j) {
                    Bts[t0 + j][ch] = tbf(o[j]);
                    pk.ob[j] = tbf(o[j] * wv_s[t0 + j]);
                }
                *(uint4*)(Bw + (size_t)chunk*(D_STATE*CHUNK) + (size_t)ch*CHUNK + t0) = pk.u;
            } else {
                #pragma unroll
                for (int j = 0; j < 8; ++j) {
                    Cts[t0 + j][ch] = tbf(o[j]);
                    A2[(size_t)chunk*(CHUNK*256) + (size_t)(t0+j)*256 + 128 + ch] =
                        tbf(o[j] * es_s[t0 + j]);
                }
            }
        }
    }
    __syncthreads();
    // G = C @ B^T from LDS (K=128), Sm epilogue -> A2[:, 0:128]
    const int lane = tid & 63, wave = tid >> 6;
    const int wm = (wave & 1) * 64, wn = (wave >> 1) * 64;
    const int lr = lane & 15, quad = lane >> 4;
    f32x4 acc[4][4];
    #pragma unroll
    for (int i = 0; i < 4; ++i)
        #pragma unroll
        for (int j = 0; j < 4; ++j) acc[i][j] = (f32x4){0.f,0.f,0.f,0.f};
    #pragma unroll
    for (int ks = 0; ks < 128; ks += 32) {
        short8 af[4], bg[4];
        #pragma unroll
        for (int i = 0; i < 4; ++i)
            af[i] = *(const short8*)(&Cts[wm + i*16 + lr][ks + quad*8]);
        #pragma unroll
        for (int j = 0; j < 4; ++j)
            bg[j] = *(const short8*)(&Bts[wn + j*16 + lr][ks + quad*8]);
        #pragma unroll
        for (int i = 0; i < 4; ++i)
            #pragma unroll
            for (int j = 0; j < 4; ++j)
                acc[i][j] = __builtin_amdgcn_mfma_f32_16x16x32_bf16(af[i], bg[j], acc[i][j], 0,0,0);
    }
    const float D0 = Dp[0];
    #pragma unroll
    for (int i = 0; i < 4; ++i)
        #pragma unroll
        for (int j = 0; j < 4; ++j)
            #pragma unroll
            for (int r = 0; r < 4; ++r) {
                int t = wm + i*16 + quad*4 + r;
                int u = wn + j*16 + lr;
                float o = 0.f;
                if (u <= t) {
                    o = acc[i][j][r] * fexp(sv_s[t] - sv_s[u]) * dt_s[u];
                    if (u == t) o += D0;
                }
                A2[(size_t)chunk*(CHUNK*256) + (size_t)t*256 + u] = tbf(o);
            }
}

// ---------- fused conv(x) -> Xt (B2 + swizzled LDS) + dH = Xt @ Bw^T ----------
// grid (8, NCHUNK), 256 threads. LDS ~65.5 KB -> 2 blocks/CU.
__global__ __launch_bounds__(256) void k_conv_xdh(
    const bf16* __restrict__ xBCin, const float* __restrict__ conv_w,
    const float* __restrict__ conv_b, const bf16* __restrict__ Bw,
    bf16* __restrict__ B2, bf16* __restrict__ dH)
{
    __shared__ __align__(16) bf16 Ls[131][128];
    __shared__ __align__(16) bf16 XsF[128 * 128];  // [p][t], t-groups XOR-swizzled by p&7
    const int chunk = blockIdx.y;
    const int p0 = blockIdx.x * 128;
    const int tid = threadIdx.x;
    const bool first = (chunk % CPB) == 0;
    const size_t rowbase = (size_t)chunk * CHUNK;
    for (int i = tid; i < 131 * 16; i += 256) {
        int r = i >> 4, cg = (i & 15) << 3;
        uint4 v = (uint4){0,0,0,0};
        if (!(first && r < 3))
            v = *(const uint4*)(xBCin + (rowbase + r - 3) * CONV_DIM + p0 + cg);
        *(uint4*)(&Ls[r][cg]) = v;
    }
    __syncthreads();
    const int p = tid & 127;
    const int half = tid >> 7;
    const int ch = p0 + p;
    float4 w = *(const float4*)(conv_w + ch * 4);
    float bias = conv_b[ch];
    bf16* outrow = B2 + (size_t)chunk * (D_INNER * 256) + (size_t)ch * 256;
    float xv[11];
    #pragma unroll
    for (int i = 0; i < 3; ++i) xv[i + 8] = fbf(Ls[half * 64 + i][p]);
    for (int v = 0; v < 8; ++v) {
        int t0 = half * 64 + v * 8;
        xv[0]=xv[8]; xv[1]=xv[9]; xv[2]=xv[10];
        #pragma unroll
        for (int i = 3; i < 11; ++i) xv[i] = fbf(Ls[t0 + i][p]);
        union { bf16 o[8]; uint4 u; } pk;
        #pragma unroll
        for (int j = 0; j < 8; ++j) {
            float a = bias + w.x*xv[j] + w.y*xv[j+1] + w.z*xv[j+2] + w.w*xv[j+3];
            pk.o[j] = tbf(fsilu(a));
        }
        *(uint4*)(outrow + t0) = pk.u;
        *(uint4*)(&XsF[p * 128 + ((((t0 >> 3) ^ (p & 7))) << 3)]) = pk.u;
    }
    __syncthreads();
    // dH[p][n] = sum_t Xs[p][t] * Bw[n][t]  (K=128; B-frags straight from global)
    const int lane = tid & 63, wave = tid >> 6;
    const int wm = (wave & 1) * 64, wn = (wave >> 1) * 64;
    const int lr = lane & 15, quad = lane >> 4;
    const bf16* bwc = Bw + (size_t)chunk * (D_STATE * CHUNK);
    f32x4 acc[4][4];
    #pragma unroll
    for (int i = 0; i < 4; ++i)
        #pragma unroll
        for (int j = 0; j < 4; ++j) acc[i][j] = (f32x4){0.f,0.f,0.f,0.f};
    #pragma unroll
    for (int ks = 0; ks < 128; ks += 32) {
        short8 af[4], bg[4];
        #pragma unroll
        for (int j = 0; j < 4; ++j)
            bg[j] = *(const short8*)(bwc + (size_t)(wn + j*16 + lr) * CHUNK + ks + quad*8);
        #pragma unroll
        for (int i = 0; i < 4; ++i)
            af[i] = *(const short8*)(&XsF[(wm + i*16 + lr) * 128 +
                                          (((((ks >> 3) + quad) ^ (lr & 7))) << 3)]);
        #pragma unroll
        for (int i = 0; i < 4; ++i)
            #pragma unroll
            for (int j = 0; j < 4; ++j)
                acc[i][j] = __builtin_amdgcn_mfma_f32_16x16x32_bf16(af[i], bg[j], acc[i][j], 0,0,0);
    }
    #pragma unroll
    for (int i = 0; i < 4; ++i)
        #pragma unroll
        for (int j = 0; j < 4; ++j)
            #pragma unroll
            for (int r = 0; r < 4; ++r) {
                int pr = p0 + wm + i*16 + quad*4 + r;
                int n  = wn + j*16 + lr;
                dH[(size_t)chunk*(D_INNER*D_STATE) + (size_t)pr*D_STATE + n] = tbf(acc[i][j][r]);
            }
}

// ---------- sequential carry over 16 chunks/batch, fully vectorized ----------
__global__ __launch_bounds__(256) void k_carry(
    const bf16* __restrict__ dH, const float* __restrict__ Pc, bf16* __restrict__ B2)
{
    int idx = blockIdx.x * 256 + threadIdx.x;   // 0..16383
    int b = blockIdx.y;
    int p = idx >> 4, ng = (idx & 15) << 3;
    uint4 v[CPB];
    float pc[CPB];
    #pragma unroll
    for (int c = 0; c < CPB; ++c)
        v[c] = *(const uint4*)(dH + (size_t)(b*CPB + c)*(D_INNER*D_STATE) + (size_t)p*D_STATE + ng);
    #pragma unroll
    for (int c = 0; c < CPB; ++c) pc[c] = Pc[b*CPB + c];
    float h[8] = {0,0,0,0,0,0,0,0};
    #pragma unroll
    for (int c = 0; c < CPB; ++c) {
        union { bf16 o[8]; uint4 u; } pk;
        #pragma unroll
        for (int k = 0; k < 8; ++k) pk.o[k] = tbf(h[k]);
        *(uint4*)(B2 + (size_t)(b*CPB + c)*(D_INNER*256) + (size_t)p*256 + 128 + ng) = pk.u;
        const bf16* vb = (const bf16*)&v[c];
        #pragma unroll
        for (int k = 0; k < 8; ++k) h[k] = pc[c]*h[k] + fbf(vb[k]);
    }
}

extern "C" void kernel_launch(void* const* d_in, const int* in_sizes, int n_in,
                              void* d_out, int out_size, void* d_ws, size_t ws_size,
                              hipStream_t stream)
{
    const float* x       = (const float*)d_in[0];
    const float* rnn     = (const float*)d_in[1];
    const float* W_in    = (const float*)d_in[2];
    const float* conv_w  = (const float*)d_in[3];
    const float* conv_b  = (const float*)d_in[4];
    const float* dt_bias = (const float*)d_in[5];
    const float* A_log   = (const float*)d_in[6];
    const float* Dp      = (const float*)d_in[7];
    const float* norm_w  = (const float*)d_in[8];
    const float* W_out   = (const float*)d_in[9];
    float* out = (float*)d_out;

    char* ws = (char*)d_ws;
    size_t off = 0;
    auto alloc = [&](size_t bytes) { void* p = ws + off; off += (bytes + 255) & ~255ULL; return p; };

    // ---- persistent ----
    bf16*  W_inbT  = (bf16*) alloc((size_t)NPROJ * D_MODEL * 2);        // 2.36M
    bf16*  W_outbT = (bf16*) alloc((size_t)D_MODEL * D_INNER * 2);      // 1.05M (norm_w folded)
    float* dts     = (float*)alloc((size_t)NROWS * 4);
    float* svec    = (float*)alloc((size_t)NROWS * 4);
    float* wvec    = (float*)alloc((size_t)NROWS * 4);
    float* esvec   = (float*)alloc((size_t)NROWS * 4);
    float* Pc      = (float*)alloc((size_t)NCHUNK * 4);
    float* ssq     = (float*)alloc((size_t)NROWS * 4);                  // RMS sumsq accum
    bf16*  zb      = (bf16*) alloc((size_t)NROWS * D_INNER * 2);        // 33.5M
    bf16*  A2      = (bf16*) alloc((size_t)NCHUNK * CHUNK * 256 * 2);   // 8.4M  [Sm | Cs]
    bf16*  B2      = (bf16*) alloc((size_t)NCHUNK * D_INNER * 256 * 2); // 67.1M [Xt | Hprev]
    bf16*  Bw      = (bf16*) alloc((size_t)NCHUNK * D_STATE * CHUNK * 2); // 4.2M
    // ---- aliased region A (50.3M): xb[0:16.8]+dH[16.8:50.3], later ybf[0:33.5] ----
    char* RA = (char*)alloc((size_t)NROWS * D_MODEL * 2 + (size_t)NROWS * D_INNER * 2);
    bf16*  xb   = (bf16*)RA;                                   // [dtcvt -> GEMM1]
    bf16*  dH   = (bf16*)(RA + (size_t)NROWS * D_MODEL * 2);   // [conv_xdh -> carry]
    bf16*  ybf  = (bf16*)RA;                                   // [Y-GEMM -> GEMM2]
    // ---- region B: xBCin [GEMM1 -> convs] ----
    bf16*  xBCin = (bf16*)alloc((size_t)NROWS * CONV_DIM * 2); // 41.9M
    // total ~200 MB

    // 1. fused convert + dt GEMV + ssq zeroing; prologue (transposes + rnn copy); prep
    k_dtcvt<<<NROWS / 4, 256, 0, stream>>>(x, W_in, dt_bias, xb, dts, ssq);
    k_prologue<<<1152 + 512 + 1, 256, 0, stream>>>(
        W_in, W_out, norm_w, rnn, W_inbT, W_outbT, out + (size_t)NROWS * D_MODEL);
    k_prep<<<NCHUNK, CHUNK, 0, stream>>>(dts, A_log, svec, wvec, esvec, Pc);

    // 2. in-projection GEMM (BK=32 depth-4, 2 blocks/CU, XCD supertile swizzle)
    k_gemm_in<<<dim3((NROWS/128) * (NPROJ/128)), 256, 0, stream>>>(xb, W_inbT, zb, xBCin);

    // 3. fused conv(B,C) + G-GEMM + Sm -> A2, Bw
    k_ssd_bc<<<NCHUNK, 256, 0, stream>>>(xBCin, conv_w, conv_b, wvec, esvec,
                                         svec, dts, Dp, Bw, A2);

    // 4. fused conv(x) -> Xt(B2) + dH-GEMM
    k_conv_xdh<<<dim3(8, NCHUNK), 256, 0, stream>>>(xBCin, conv_w, conv_b, Bw, B2, dH);

    // 5. carry states -> Hprev region of B2
    k_carry<<<dim3(64, BATCH), 256, 0, stream>>>(dH, Pc, B2);

    // 6. Y = [Sm|Cs] @ [Xt|Hprev]^T (K=256) -> gated bf16 ybf + row sumsq atomics
    k_bgemm<2><<<dim3(1, D_INNER/128, NCHUNK), 256, 0, stream>>>(
        A2, 256, (size_t)CHUNK*256,
        B2, 256, (size_t)D_INNER*256,
        ybf, D_INNER, (size_t)CHUNK*D_INNER, 256, zb, ssq);

    // 7. out-projection GEMM with RMS post-scale epilogue -> d_out (bm-fastest grid)
    k_bgemm<3><<<dim3(NROWS/128, D_MODEL/128, 1), 256, 0, stream>>>(
        ybf, D_INNER, 0, W_outbT, D_INNER, 0, out, D_MODEL, 0, D_INNER,
        nullptr, ssq);
}

// Round 9
// 275.267 us; speedup vs baseline: 1.0889x; 1.0889x over previous
//
#include <hip/hip_runtime.h>
#include <hip/hip_bf16.h>
#include <math.h>

#define D_MODEL 512
#define D_INNER 1024
#define D_STATE 128
#define CONV_DIM (D_INNER + 2*D_STATE)        // 1280
#define D_IN_PROJ (2*D_INNER + 2*D_STATE + 1) // 2305
#define NPROJ 2304                            // z + xBC cols (dt col via GEMV)
#define BATCH 8
#define SEQ 2048
#define NROWS (BATCH*SEQ)                     // 16384
#define CHUNK 128
#define NCHUNK (NROWS/CHUNK)                  // 128 total (16 per batch)
#define CPB (SEQ/CHUNK)                       // 16 chunks per batch
#define EPS_RMS 1e-5f

typedef __hip_bfloat16 bf16;
typedef __attribute__((ext_vector_type(8))) short short8;
typedef __attribute__((ext_vector_type(4))) float f32x4;

__device__ __forceinline__ float fbf(bf16 v) { return __bfloat162float(v); }
__device__ __forceinline__ bf16 tbf(float v) { return __float2bfloat16(v); }
__device__ __forceinline__ float fexp(float x) { return __expf(x); }          // v_exp_f32
__device__ __forceinline__ float frcp(float x) { return __builtin_amdgcn_rcpf(x); }
__device__ __forceinline__ float fsilu(float a) { return a * frcp(1.f + fexp(-a)); }

// async global->LDS, 16B per lane; LDS dest is wave-uniform base + lane*16
__device__ __forceinline__ void gl2lds16(const bf16* g, bf16* l) {
    __builtin_amdgcn_global_load_lds(
        (const __attribute__((address_space(1))) unsigned int*)g,
        (__attribute__((address_space(3))) unsigned int*)l, 16, 0, 0);
}

// ---------- prologue: both weight transposes (+norm_w fold) + rnn tail copy ----------
// 1D grid: [0,1152) = W_in^T tiles, [1152,1664) = W_out^T tiles, 1664 = rnn copy.
__global__ __launch_bounds__(256) void k_prologue(
    const float* __restrict__ W_in, const float* __restrict__ W_out,
    const float* __restrict__ norm_w, const float* __restrict__ rnn,
    bf16* __restrict__ W_inbT, bf16* __restrict__ W_outbT, float* __restrict__ outTail)
{
    int b = blockIdx.x;
    if (b == 1152 + 512) {  // rnn passthrough: 8*512 fp32
        int tid = threadIdx.x;
        #pragma unroll
        for (int i = 0; i < 4; ++i)
            *(float4*)(outTail + (tid + i * 256) * 4) =
                *(const float4*)(rnn + (tid + i * 256) * 4);
        return;
    }
    __shared__ float tile[32][33];
    const float* src; bf16* dst; const float* scale;
    int c0, r0, sstride, C;
    if (b < 1152) {           // W_in[D_MODEL][D_IN_PROJ] -> W_inbT[NPROJ][D_MODEL]
        src = W_in; dst = W_inbT; scale = nullptr;
        c0 = (b % 16) * 32; r0 = (b / 16) * 32; sstride = D_IN_PROJ; C = D_MODEL;
    } else {                  // W_out[D_INNER][D_MODEL] -> W_outbT[D_MODEL][D_INNER], *norm_w
        int bb = b - 1152;
        src = W_out; dst = W_outbT; scale = norm_w;
        c0 = (bb % 32) * 32; r0 = (bb / 32) * 32; sstride = D_MODEL; C = D_INNER;
    }
    int tx = threadIdx.x & 31, ty = threadIdx.x >> 5;
    #pragma unroll
    for (int i = 0; i < 32; i += 8) {
        float s = scale ? scale[c0 + ty + i] : 1.f;
        tile[ty + i][tx] = src[(size_t)(c0 + ty + i) * sstride + (r0 + tx)] * s;
    }
    __syncthreads();
    #pragma unroll
    for (int i = 0; i < 32; i += 8)
        dst[(size_t)(r0 + ty + i) * C + (c0 + tx)] = tbf(tile[tx][ty + i]);
}

// ---------- fused x->bf16 convert + dt GEMV + softplus + ssq zeroing ----------
__global__ __launch_bounds__(256) void k_dtcvt(
    const float* __restrict__ x, const float* __restrict__ W_in,
    const float* __restrict__ dt_bias,
    bf16* __restrict__ xb, float* __restrict__ dts, float* __restrict__ ssq)
{
    __shared__ float wcol[D_MODEL];
    int tid = threadIdx.x;
    wcol[tid]       = W_in[(size_t)tid * D_IN_PROJ + 2304];
    wcol[tid + 256] = W_in[(size_t)(tid + 256) * D_IN_PROJ + 2304];
    __syncthreads();
    int row  = blockIdx.x * 4 + (tid >> 6);
    int lane = tid & 63;
    const float* xr = x + (size_t)row * D_MODEL;
    float4 a = *(const float4*)(xr + lane * 8);
    float4 b = *(const float4*)(xr + lane * 8 + 4);
    union { bf16 o[8]; uint4 u; } pk;
    pk.o[0]=tbf(a.x); pk.o[1]=tbf(a.y); pk.o[2]=tbf(a.z); pk.o[3]=tbf(a.w);
    pk.o[4]=tbf(b.x); pk.o[5]=tbf(b.y); pk.o[6]=tbf(b.z); pk.o[7]=tbf(b.w);
    *(uint4*)(xb + (size_t)row * D_MODEL + lane * 8) = pk.u;
    const float* wc = wcol + lane * 8;
    float s = a.x*wc[0]+a.y*wc[1]+a.z*wc[2]+a.w*wc[3]
            + b.x*wc[4]+b.y*wc[5]+b.z*wc[6]+b.w*wc[7];
    #pragma unroll
    for (int off = 32; off; off >>= 1) s += __shfl_xor(s, off);
    if (lane == 0) {
        float raw = s + dt_bias[0];
        dts[row] = raw > 20.f ? raw : log1pf(fexp(raw));
        ssq[row] = 0.f;
    }
}

// ---------- batched NT GEMM, 128x128 tile, BK=64, LDS double-buffer + counted vmcnt ----------
// (round-2 proven config: 256 thr, 4 waves, 64 KiB LDS -> 2 blocks/CU, vmcnt(8) dist-2)
// MODE 0: fp32 out.  MODE 1: bf16 out.
// MODE 2: Y-epilogue — gate with silu(zg), bf16 out, ssq atomics. bm==0, bi=blockIdx.x
//         (chunk-FASTEST grid: the 8 bn-blocks sharing one A2 chunk sit at id stride
//          128 = 0 mod 8 -> same XCD, co-resident -> A2 tile L2-hot, not refetched 8x.)
// MODE 3: fp32 out scaled by rsqrt(ssq[row]/D_INNER + eps). Grid bm-fastest:
//         the 4 readers of each A-panel are {b,b+128,b+256,b+384} -> same XCD,
//         co-resident -> A fetched once. (bn-fastest swap measured -11 us: do not.)
template<int MODE>
__global__ __launch_bounds__(256) void k_bgemm(
    const bf16* __restrict__ A, int lda, size_t sA,
    const bf16* __restrict__ Bt, int ldb, size_t sB,
    void* __restrict__ Cv, int ldc, size_t sC, int K,
    const bf16* __restrict__ zg, float* __restrict__ ssq)
{
    constexpr int BK = 64;
    __shared__ __align__(16) bf16 SM[4 * 8192];   // As0|Bs0|As1|Bs1 = 64 KiB (2 blocks/CU)
    const int tid = threadIdx.x, lane = tid & 63, wave = tid >> 6;
    const int wm = (wave & 1) * 64, wn = (wave >> 1) * 64;
    const int lr = lane & 15, quad = lane >> 4;
    const int rx = lr & 7;
    size_t bm, bn, bi;
    if (MODE == 2)      { bm = 0; bn = (size_t)blockIdx.y * 128; bi = blockIdx.x; }
    else                { bm = (size_t)blockIdx.x * 128; bn = (size_t)blockIdx.y * 128; bi = blockIdx.z; }
    A  += bi * sA;
    Bt += bi * sB;
    const int srow = lane >> 3;
    const int scol = (((lane & 7) ^ srow) << 3);

    f32x4 acc[4][4];
    #pragma unroll
    for (int i = 0; i < 4; ++i)
        #pragma unroll
        for (int j = 0; j < 4; ++j) acc[i][j] = (f32x4){0.f,0.f,0.f,0.f};

    auto stage = [&](bf16* Ad, bf16* Bd, int k0) {
        #pragma unroll
        for (int q = 0; q < 4; ++q) {
            int rg = wave * 32 + q * 8;
            gl2lds16(A  + (bm + rg + srow) * lda + k0 + scol, Ad + rg * BK);
            gl2lds16(Bt + (bn + rg + srow) * ldb + k0 + scol, Bd + rg * BK);
        }
    };

    const int NT = K / BK;
    stage(SM, SM + 8192, 0);                       // tile 0 -> buf0
    if (NT > 1) stage(SM + 16384, SM + 24576, BK); // tile 1 -> buf1

    for (int kt = 0; kt < NT; ++kt) {
        if (kt + 1 < NT) asm volatile("s_waitcnt vmcnt(8)" ::: "memory");
        else             asm volatile("s_waitcnt vmcnt(0)" ::: "memory");
        __builtin_amdgcn_s_barrier();
        __builtin_amdgcn_sched_barrier(0);
        const bf16* As = SM + (kt & 1) * 16384;
        const bf16* Bs = As + 8192;
        #pragma unroll
        for (int ks = 0; ks < BK; ks += 32) {
            const int off = ((((ks >> 3) + quad) ^ rx) << 3);
            short8 af[4], bg[4];
            #pragma unroll
            for (int i = 0; i < 4; ++i)
                af[i] = *(const short8*)(As + (wm + i*16 + lr) * BK + off);
            #pragma unroll
            for (int j = 0; j < 4; ++j)
                bg[j] = *(const short8*)(Bs + (wn + j*16 + lr) * BK + off);
            #pragma unroll
            for (int i = 0; i < 4; ++i)
                #pragma unroll
                for (int j = 0; j < 4; ++j)
                    acc[i][j] = __builtin_amdgcn_mfma_f32_16x16x32_bf16(af[i], bg[j], acc[i][j], 0,0,0);
        }
        __builtin_amdgcn_sched_barrier(0);
        __builtin_amdgcn_s_barrier();
        if (kt + 2 < NT) {
            bf16* An = SM + (kt & 1) * 16384;
            stage(An, An + 8192, (kt + 2) * BK);
        }
    }
    if (MODE <= 1) {
        #pragma unroll
        for (int i = 0; i < 4; ++i)
            #pragma unroll
            for (int j = 0; j < 4; ++j)
                #pragma unroll
                for (int r = 0; r < 4; ++r) {
                    size_t row = bm + wm + i*16 + quad*4 + r;
                    size_t col = bn + wn + j*16 + lr;
                    float v = acc[i][j][r];
                    if (MODE == 0) ((float*)Cv + bi*sC)[row * ldc + col] = v;
                    else           ((bf16*)Cv + bi*sC)[row * ldc + col] = tbf(v);
                }
    } else if (MODE == 2) {
        // stage zg tile (128 rows x 128 cols, XOR-swizzled) into SM, reusing buf0
        const size_t tokbase = bi * CHUNK;
        const bf16* zrow = zg + tokbase * D_INNER + bn;
        __syncthreads();
        #pragma unroll
        for (int q = 0; q < 8; ++q) {
            int r0 = wave * 32 + q * 4;
            int rr = r0 + (lane >> 4);
            int gl = (lane & 15) ^ (rr & 7);
            gl2lds16(zrow + (size_t)rr * D_INNER + gl * 8, SM + r0 * 128);
        }
        __syncthreads();
        float srw[4][4];
        #pragma unroll
        for (int i = 0; i < 4; ++i)
            #pragma unroll
            for (int r = 0; r < 4; ++r) srw[i][r] = 0.f;
        #pragma unroll
        for (int i = 0; i < 4; ++i)
            #pragma unroll
            for (int j = 0; j < 4; ++j)
                #pragma unroll
                for (int r = 0; r < 4; ++r) {
                    int row = wm + i*16 + quad*4 + r;       // 0..127 (bm==0)
                    int col = wn + j*16 + lr;               // 0..127 local
                    int gph = ((col >> 3) ^ (row & 7));
                    float z = fbf(SM[row * 128 + (gph << 3) + (col & 7)]);
                    float g = acc[i][j][r] * z * frcp(1.f + fexp(-z));
                    ((bf16*)Cv + bi*sC)[(size_t)row * ldc + bn + col] = tbf(g);
                    srw[i][r] += g * g;
                }
        #pragma unroll
        for (int i = 0; i < 4; ++i)
            #pragma unroll
            for (int r = 0; r < 4; ++r) {
                float s = srw[i][r];
                s += __shfl_xor(s, 1);
                s += __shfl_xor(s, 2);
                s += __shfl_xor(s, 4);
                s += __shfl_xor(s, 8);
                if (lr == 0)
                    atomicAdd(ssq + tokbase + wm + i*16 + quad*4 + r, s);
            }
    } else {  // MODE 3
        #pragma unroll
        for (int i = 0; i < 4; ++i)
            #pragma unroll
            for (int r = 0; r < 4; ++r) {
                size_t row = bm + wm + i*16 + quad*4 + r;
                float sc = rsqrtf(ssq[row] * (1.f / D_INNER) + EPS_RMS);
                #pragma unroll
                for (int j = 0; j < 4; ++j) {
                    size_t col = bn + wn + j*16 + lr;
                    ((float*)Cv + bi*sC)[row * ldc + col] = acc[i][j][r] * sc;
                }
            }
    }
}

// ---------- GEMM1 with split output: cols<1024 -> zb, else xBCin ----------
// (round-2 exact config — session best 53.3 us. Six schedule variants tried and all
//  lost: 256^2 4-phase x2 (63-64), depth-4 512thr (64), BK=32 x2 (59, 66).
//  The 2-barrier family is barrier-rate-bound: dist-2/BK=64 minimizes NT at 2 blk/CU.)
__global__ __launch_bounds__(256) void k_gemm_in(
    const bf16* __restrict__ A, const bf16* __restrict__ Bt,
    bf16* __restrict__ zb, bf16* __restrict__ xBCin)
{
    constexpr int BK = 64;
    constexpr int K = D_MODEL;
    constexpr int NT = K / BK;                    // 8
    __shared__ __align__(16) bf16 SM[4 * 8192];   // 64 KiB -> 2 blocks/CU
    const int tid = threadIdx.x, lane = tid & 63, wave = tid >> 6;
    const int wm = (wave & 1) * 64, wn = (wave >> 1) * 64;
    const int lr = lane & 15, quad = lane >> 4;
    const int rx = lr & 7;
    const size_t bm = (size_t)blockIdx.x * 128;
    const int bn = blockIdx.y * 128;
    const int srow = lane >> 3;
    const int scol = (((lane & 7) ^ srow) << 3);

    f32x4 acc[4][4];
    #pragma unroll
    for (int i = 0; i < 4; ++i)
        #pragma unroll
        for (int j = 0; j < 4; ++j) acc[i][j] = (f32x4){0.f,0.f,0.f,0.f};

    auto stage = [&](bf16* Ad, bf16* Bd, int k0) {
        #pragma unroll
        for (int q = 0; q < 4; ++q) {
            int rg = wave * 32 + q * 8;
            gl2lds16(A  + (bm + rg + srow) * K + k0 + scol, Ad + rg * BK);
            gl2lds16(Bt + ((size_t)bn + rg + srow) * K + k0 + scol, Bd + rg * BK);
        }
    };

    stage(SM, SM + 8192, 0);
    stage(SM + 16384, SM + 24576, BK);

    for (int kt = 0; kt < NT; ++kt) {
        if (kt + 1 < NT) asm volatile("s_waitcnt vmcnt(8)" ::: "memory");
        else             asm volatile("s_waitcnt vmcnt(0)" ::: "memory");
        __builtin_amdgcn_s_barrier();
        __builtin_amdgcn_sched_barrier(0);
        const bf16* As = SM + (kt & 1) * 16384;
        const bf16* Bs = As + 8192;
        #pragma unroll
        for (int ks = 0; ks < BK; ks += 32) {
            const int off = ((((ks >> 3) + quad) ^ rx) << 3);
            short8 af[4], bg[4];
            #pragma unroll
            for (int i = 0; i < 4; ++i)
                af[i] = *(const short8*)(As + (wm + i*16 + lr) * BK + off);
            #pragma unroll
            for (int j = 0; j < 4; ++j)
                bg[j] = *(const short8*)(Bs + (wn + j*16 + lr) * BK + off);
            #pragma unroll
            for (int i = 0; i < 4; ++i)
                #pragma unroll
                for (int j = 0; j < 4; ++j)
                    acc[i][j] = __builtin_amdgcn_mfma_f32_16x16x32_bf16(af[i], bg[j], acc[i][j], 0,0,0);
        }
        __builtin_amdgcn_sched_barrier(0);
        __builtin_amdgcn_s_barrier();
        if (kt + 2 < NT) {
            bf16* An = SM + (kt & 1) * 16384;
            stage(An, An + 8192, (kt + 2) * BK);
        }
    }
    #pragma unroll
    for (int i = 0; i < 4; ++i)
        #pragma unroll
        for (int j = 0; j < 4; ++j)
            #pragma unroll
            for (int r = 0; r < 4; ++r) {
                size_t row = bm + wm + i*16 + quad*4 + r;
                int col = bn + wn + j*16 + lr;
                float v = acc[i][j][r];
                if (col < D_INNER) zb[row * D_INNER + col] = tbf(v);
                else xBCin[row * CONV_DIM + (col - D_INNER)] = tbf(v);
            }
}

// ---------- per-chunk cumsum of a_t = A*dt, decay factors ----------
__global__ void k_prep(const float* __restrict__ dts, const float* __restrict__ A_log,
                       float* __restrict__ svec, float* __restrict__ wvec,
                       float* __restrict__ esvec, float* __restrict__ Pc)
{
    int chunk = blockIdx.x, t = threadIdx.x;  // 128 threads
    int row = chunk * CHUNK + t;
    float A = -fexp(A_log[0]);
    __shared__ float sh[CHUNK];
    sh[t] = A * dts[row];
    __syncthreads();
    for (int off = 1; off < CHUNK; off <<= 1) {
        float v = (t >= off) ? sh[t - off] : 0.f;
        __syncthreads();
        sh[t] += v;
        __syncthreads();
    }
    float s = sh[t], sL = sh[CHUNK - 1];
    svec[row]  = s;
    wvec[row]  = fexp(sL - s) * dts[row];
    esvec[row] = fexp(s);
    if (t == CHUNK - 1) Pc[chunk] = fexp(sL);
}

// ---------- fused conv(B,C) + G = C@B^T + Sm epilogue + Bw/Cs builds ----------
// grid NCHUNK, 256 threads.
__global__ __launch_bounds__(256) void k_ssd_bc(
    const bf16* __restrict__ xBCin, const float* __restrict__ conv_w,
    const float* __restrict__ conv_b, const float* __restrict__ wvec,
    const float* __restrict__ esvec, const float* __restrict__ svec,
    const float* __restrict__ dts, const float* __restrict__ Dp,
    bf16* __restrict__ Bw, bf16* __restrict__ A2)
{
    __shared__ __align__(16) bf16 Ls[131][128];
    __shared__ __align__(16) bf16 Bts[128][136];
    __shared__ __align__(16) bf16 Cts[128][136];
    __shared__ float sv_s[128], dt_s[128], wv_s[128], es_s[128];
    const int chunk = blockIdx.x;
    const int tid = threadIdx.x;
    const bool first = (chunk % CPB) == 0;
    const size_t rowbase = (size_t)chunk * CHUNK;
    if (tid < 128) {
        sv_s[tid] = svec[rowbase + tid];
        dt_s[tid] = dts[rowbase + tid];
        wv_s[tid] = wvec[rowbase + tid];
        es_s[tid] = esvec[rowbase + tid];
    }
    const int ch  = tid & 127;
    const int seg = tid >> 7;   // t-half

    #pragma unroll
    for (int phase = 0; phase < 2; ++phase) {
        const int coff = D_INNER + phase * 128;   // B then C channel base
        __syncthreads();
        for (int i = tid; i < 131 * 16; i += 256) {
            int r = i >> 4, cg = (i & 15) << 3;
            uint4 v = (uint4){0,0,0,0};
            if (!(first && r < 3))
                v = *(const uint4*)(xBCin + (rowbase + r - 3) * CONV_DIM + coff + cg);
            *(uint4*)(&Ls[r][cg]) = v;
        }
        __syncthreads();
        float4 w = *(const float4*)(conv_w + (coff + ch) * 4);
        float bias = conv_b[coff + ch];
        float xv[11];
        #pragma unroll
        for (int i = 0; i < 3; ++i) xv[i + 8] = fbf(Ls[seg * 64 + i][ch]);
        for (int v = 0; v < 8; ++v) {
            int t0 = seg * 64 + v * 8;
            xv[0]=xv[8]; xv[1]=xv[9]; xv[2]=xv[10];
            #pragma unroll
            for (int i = 3; i < 11; ++i) xv[i] = fbf(Ls[t0 + i][ch]);
            float o[8];
            #pragma unroll
            for (int j = 0; j < 8; ++j) {
                float a = bias + w.x*xv[j] + w.y*xv[j+1] + w.z*xv[j+2] + w.w*xv[j+3];
                o[j] = fsilu(a);
            }
            if (phase == 0) {
                union { bf16 ob[8]; uint4 u; } pk;
                #pragma unroll
                for (int j = 0; j < 8; ++j) {
                    Bts[t0 + j][ch] = tbf(o[j]);
                    pk.ob[j] = tbf(o[j] * wv_s[t0 + j]);
                }
                *(uint4*)(Bw + (size_t)chunk*(D_STATE*CHUNK) + (size_t)ch*CHUNK + t0) = pk.u;
            } else {
                #pragma unroll
                for (int j = 0; j < 8; ++j) {
                    Cts[t0 + j][ch] = tbf(o[j]);
                    A2[(size_t)chunk*(CHUNK*256) + (size_t)(t0+j)*256 + 128 + ch] =
                        tbf(o[j] * es_s[t0 + j]);
                }
            }
        }
    }
    __syncthreads();
    // G = C @ B^T from LDS (K=128), Sm epilogue -> A2[:, 0:128]
    const int lane = tid & 63, wave = tid >> 6;
    const int wm = (wave & 1) * 64, wn = (wave >> 1) * 64;
    const int lr = lane & 15, quad = lane >> 4;
    f32x4 acc[4][4];
    #pragma unroll
    for (int i = 0; i < 4; ++i)
        #pragma unroll
        for (int j = 0; j < 4; ++j) acc[i][j] = (f32x4){0.f,0.f,0.f,0.f};
    #pragma unroll
    for (int ks = 0; ks < 128; ks += 32) {
        short8 af[4], bg[4];
        #pragma unroll
        for (int i = 0; i < 4; ++i)
            af[i] = *(const short8*)(&Cts[wm + i*16 + lr][ks + quad*8]);
        #pragma unroll
        for (int j = 0; j < 4; ++j)
            bg[j] = *(const short8*)(&Bts[wn + j*16 + lr][ks + quad*8]);
        #pragma unroll
        for (int i = 0; i < 4; ++i)
            #pragma unroll
            for (int j = 0; j < 4; ++j)
                acc[i][j] = __builtin_amdgcn_mfma_f32_16x16x32_bf16(af[i], bg[j], acc[i][j], 0,0,0);
    }
    const float D0 = Dp[0];
    #pragma unroll
    for (int i = 0; i < 4; ++i)
        #pragma unroll
        for (int j = 0; j < 4; ++j)
            #pragma unroll
            for (int r = 0; r < 4; ++r) {
                int t = wm + i*16 + quad*4 + r;
                int u = wn + j*16 + lr;
                float o = 0.f;
                if (u <= t) {
                    o = acc[i][j][r] * fexp(sv_s[t] - sv_s[u]) * dt_s[u];
                    if (u == t) o += D0;
                }
                A2[(size_t)chunk*(CHUNK*256) + (size_t)t*256 + u] = tbf(o);
            }
}

// ---------- fused conv(x) -> Xt (B2 + swizzled LDS) + dH = Xt @ Bw^T ----------
// grid (NCHUNK, 8), 256 threads — chunk-FASTEST so the 8 p0-blocks sharing one
// chunk's Bw tile sit at id stride 128 = 0 mod 8 -> same XCD, co-resident.
__global__ __launch_bounds__(256) void k_conv_xdh(
    const bf16* __restrict__ xBCin, const float* __restrict__ conv_w,
    const float* __restrict__ conv_b, const bf16* __restrict__ Bw,
    bf16* __restrict__ B2, bf16* __restrict__ dH)
{
    __shared__ __align__(16) bf16 Ls[131][128];
    __shared__ __align__(16) bf16 XsF[128 * 128];  // [p][t], t-groups XOR-swizzled by p&7
    const int chunk = blockIdx.x;
    const int p0 = blockIdx.y * 128;
    const int tid = threadIdx.x;
    const bool first = (chunk % CPB) == 0;
    const size_t rowbase = (size_t)chunk * CHUNK;
    for (int i = tid; i < 131 * 16; i += 256) {
        int r = i >> 4, cg = (i & 15) << 3;
        uint4 v = (uint4){0,0,0,0};
        if (!(first && r < 3))
            v = *(const uint4*)(xBCin + (rowbase + r - 3) * CONV_DIM + p0 + cg);
        *(uint4*)(&Ls[r][cg]) = v;
    }
    __syncthreads();
    const int p = tid & 127;
    const int half = tid >> 7;
    const int ch = p0 + p;
    float4 w = *(const float4*)(conv_w + ch * 4);
    float bias = conv_b[ch];
    bf16* outrow = B2 + (size_t)chunk * (D_INNER * 256) + (size_t)ch * 256;
    float xv[11];
    #pragma unroll
    for (int i = 0; i < 3; ++i) xv[i + 8] = fbf(Ls[half * 64 + i][p]);
    for (int v = 0; v < 8; ++v) {
        int t0 = half * 64 + v * 8;
        xv[0]=xv[8]; xv[1]=xv[9]; xv[2]=xv[10];
        #pragma unroll
        for (int i = 3; i < 11; ++i) xv[i] = fbf(Ls[t0 + i][p]);
        union { bf16 o[8]; uint4 u; } pk;
        #pragma unroll
        for (int j = 0; j < 8; ++j) {
            float a = bias + w.x*xv[j] + w.y*xv[j+1] + w.z*xv[j+2] + w.w*xv[j+3];
            pk.o[j] = tbf(fsilu(a));
        }
        *(uint4*)(outrow + t0) = pk.u;
        *(uint4*)(&XsF[p * 128 + ((((t0 >> 3) ^ (p & 7))) << 3)]) = pk.u;
    }
    __syncthreads();
    // dH[p][n] = sum_t Xs[p][t] * Bw[n][t]  (K=128; B-frags straight from global)
    const int lane = tid & 63, wave = tid >> 6;
    const int wm = (wave & 1) * 64, wn = (wave >> 1) * 64;
    const int lr = lane & 15, quad = lane >> 4;
    const bf16* bwc = Bw + (size_t)chunk * (D_STATE * CHUNK);
    f32x4 acc[4][4];
    #pragma unroll
    for (int i = 0; i < 4; ++i)
        #pragma unroll
        for (int j = 0; j < 4; ++j) acc[i][j] = (f32x4){0.f,0.f,0.f,0.f};
    #pragma unroll
    for (int ks = 0; ks < 128; ks += 32) {
        short8 af[4], bg[4];
        #pragma unroll
        for (int j = 0; j < 4; ++j)
            bg[j] = *(const short8*)(bwc + (size_t)(wn + j*16 + lr) * CHUNK + ks + quad*8);
        #pragma unroll
        for (int i = 0; i < 4; ++i)
            af[i] = *(const short8*)(&XsF[(wm + i*16 + lr) * 128 +
                                          (((((ks >> 3) + quad) ^ (lr & 7))) << 3)]);
        #pragma unroll
        for (int i = 0; i < 4; ++i)
            #pragma unroll
            for (int j = 0; j < 4; ++j)
                acc[i][j] = __builtin_amdgcn_mfma_f32_16x16x32_bf16(af[i], bg[j], acc[i][j], 0,0,0);
    }
    #pragma unroll
    for (int i = 0; i < 4; ++i)
        #pragma unroll
        for (int j = 0; j < 4; ++j)
            #pragma unroll
            for (int r = 0; r < 4; ++r) {
                int pr = p0 + wm + i*16 + quad*4 + r;
                int n  = wn + j*16 + lr;
                dH[(size_t)chunk*(D_INNER*D_STATE) + (size_t)pr*D_STATE + n] = tbf(acc[i][j][r]);
            }
}

// ---------- sequential carry over 16 chunks/batch, fully vectorized ----------
__global__ __launch_bounds__(256) void k_carry(
    const bf16* __restrict__ dH, const float* __restrict__ Pc, bf16* __restrict__ B2)
{
    int idx = blockIdx.x * 256 + threadIdx.x;   // 0..16383
    int b = blockIdx.y;
    int p = idx >> 4, ng = (idx & 15) << 3;
    uint4 v[CPB];
    float pc[CPB];
    #pragma unroll
    for (int c = 0; c < CPB; ++c)
        v[c] = *(const uint4*)(dH + (size_t)(b*CPB + c)*(D_INNER*D_STATE) + (size_t)p*D_STATE + ng);
    #pragma unroll
    for (int c = 0; c < CPB; ++c) pc[c] = Pc[b*CPB + c];
    float h[8] = {0,0,0,0,0,0,0,0};
    #pragma unroll
    for (int c = 0; c < CPB; ++c) {
        union { bf16 o[8]; uint4 u; } pk;
        #pragma unroll
        for (int k = 0; k < 8; ++k) pk.o[k] = tbf(h[k]);
        *(uint4*)(B2 + (size_t)(b*CPB + c)*(D_INNER*256) + (size_t)p*256 + 128 + ng) = pk.u;
        const bf16* vb = (const bf16*)&v[c];
        #pragma unroll
        for (int k = 0; k < 8; ++k) h[k] = pc[c]*h[k] + fbf(vb[k]);
    }
}

extern "C" void kernel_launch(void* const* d_in, const int* in_sizes, int n_in,
                              void* d_out, int out_size, void* d_ws, size_t ws_size,
                              hipStream_t stream)
{
    const float* x       = (const float*)d_in[0];
    const float* rnn     = (const float*)d_in[1];
    const float* W_in    = (const float*)d_in[2];
    const float* conv_w  = (const float*)d_in[3];
    const float* conv_b  = (const float*)d_in[4];
    const float* dt_bias = (const float*)d_in[5];
    const float* A_log   = (const float*)d_in[6];
    const float* Dp      = (const float*)d_in[7];
    const float* norm_w  = (const float*)d_in[8];
    const float* W_out   = (const float*)d_in[9];
    float* out = (float*)d_out;

    char* ws = (char*)d_ws;
    size_t off = 0;
    auto alloc = [&](size_t bytes) { void* p = ws + off; off += (bytes + 255) & ~255ULL; return p; };

    // ---- persistent ----
    bf16*  W_inbT  = (bf16*) alloc((size_t)NPROJ * D_MODEL * 2);        // 2.36M
    bf16*  W_outbT = (bf16*) alloc((size_t)D_MODEL * D_INNER * 2);      // 1.05M (norm_w folded)
    float* dts     = (float*)alloc((size_t)NROWS * 4);
    float* svec    = (float*)alloc((size_t)NROWS * 4);
    float* wvec    = (float*)alloc((size_t)NROWS * 4);
    float* esvec   = (float*)alloc((size_t)NROWS * 4);
    float* Pc      = (float*)alloc((size_t)NCHUNK * 4);
    float* ssq     = (float*)alloc((size_t)NROWS * 4);                  // RMS sumsq accum
    bf16*  zb      = (bf16*) alloc((size_t)NROWS * D_INNER * 2);        // 33.5M
    bf16*  A2      = (bf16*) alloc((size_t)NCHUNK * CHUNK * 256 * 2);   // 8.4M  [Sm | Cs]
    bf16*  B2      = (bf16*) alloc((size_t)NCHUNK * D_INNER * 256 * 2); // 67.1M [Xt | Hprev]
    bf16*  Bw      = (bf16*) alloc((size_t)NCHUNK * D_STATE * CHUNK * 2); // 4.2M
    // ---- aliased region A (50.3M): xb[0:16.8]+dH[16.8:50.3], later ybf[0:33.5] ----
    char* RA = (char*)alloc((size_t)NROWS * D_MODEL * 2 + (size_t)NROWS * D_INNER * 2);
    bf16*  xb   = (bf16*)RA;                                   // [dtcvt -> GEMM1]
    bf16*  dH   = (bf16*)(RA + (size_t)NROWS * D_MODEL * 2);   // [conv_xdh -> carry]
    bf16*  ybf  = (bf16*)RA;                                   // [Y-GEMM -> GEMM2]
    // ---- region B: xBCin [GEMM1 -> convs] ----
    bf16*  xBCin = (bf16*)alloc((size_t)NROWS * CONV_DIM * 2); // 41.9M
    // total ~200 MB

    // 1. fused convert + dt GEMV + ssq zeroing; prologue (transposes + rnn copy); prep
    k_dtcvt<<<NROWS / 4, 256, 0, stream>>>(x, W_in, dt_bias, xb, dts, ssq);
    k_prologue<<<1152 + 512 + 1, 256, 0, stream>>>(
        W_in, W_out, norm_w, rnn, W_inbT, W_outbT, out + (size_t)NROWS * D_MODEL);
    k_prep<<<NCHUNK, CHUNK, 0, stream>>>(dts, A_log, svec, wvec, esvec, Pc);

    // 2. in-projection GEMM with split output (round-2 proven config)
    k_gemm_in<<<dim3(NROWS/128, NPROJ/128), 256, 0, stream>>>(xb, W_inbT, zb, xBCin);

    // 3. fused conv(B,C) + G-GEMM + Sm -> A2, Bw
    k_ssd_bc<<<NCHUNK, 256, 0, stream>>>(xBCin, conv_w, conv_b, wvec, esvec,
                                         svec, dts, Dp, Bw, A2);

    // 4. fused conv(x) -> Xt(B2) + dH-GEMM (chunk-fastest grid: Bw shared on one XCD)
    k_conv_xdh<<<dim3(NCHUNK, 8), 256, 0, stream>>>(xBCin, conv_w, conv_b, Bw, B2, dH);

    // 5. carry states -> Hprev region of B2
    k_carry<<<dim3(64, BATCH), 256, 0, stream>>>(dH, Pc, B2);

    // 6. Y = [Sm|Cs] @ [Xt|Hprev]^T (K=256) -> gated bf16 ybf + row sumsq atomics
    //    (chunk-fastest grid: the 8 bn-blocks sharing one A2 chunk land on one XCD)
    k_bgemm<2><<<dim3(NCHUNK, D_INNER/128, 1), 256, 0, stream>>>(
        A2, 256, (size_t)CHUNK*256,
        B2, 256, (size_t)D_INNER*256,
        ybf, D_INNER, (size_t)CHUNK*D_INNER, 256, zb, ssq);

    // 7. out-projection GEMM with RMS post-scale epilogue -> d_out (bm-fastest grid)
    k_bgemm<3><<<dim3(NROWS/128, D_MODEL/128, 1), 256, 0, stream>>>(
        ybf, D_INNER, 0, W_outbT, D_INNER, 0, out, D_MODEL, 0, D_INNER,
        nullptr, ssq);
}

// Round 10
// 265.147 us; speedup vs baseline: 1.1305x; 1.0382x over previous
//
#include <hip/hip_runtime.h>
#include <hip/hip_bf16.h>
#include <math.h>

#define D_MODEL 512
#define D_INNER 1024
#define D_STATE 128
#define CONV_DIM (D_INNER + 2*D_STATE)        // 1280
#define D_IN_PROJ (2*D_INNER + 2*D_STATE + 1) // 2305
#define NPROJ 2304                            // z + xBC cols (dt col via GEMV)
#define BATCH 8
#define SEQ 2048
#define NROWS (BATCH*SEQ)                     // 16384
#define CHUNK 128
#define NCHUNK (NROWS/CHUNK)                  // 128 total (16 per batch)
#define CPB (SEQ/CHUNK)                       // 16 chunks per batch
#define EPS_RMS 1e-5f

typedef __hip_bfloat16 bf16;
typedef __attribute__((ext_vector_type(8))) short short8;
typedef __attribute__((ext_vector_type(4))) float f32x4;

__device__ __forceinline__ float fbf(bf16 v) { return __bfloat162float(v); }
__device__ __forceinline__ bf16 tbf(float v) { return __float2bfloat16(v); }
__device__ __forceinline__ float fexp(float x) { return __expf(x); }          // v_exp_f32
__device__ __forceinline__ float frcp(float x) { return __builtin_amdgcn_rcpf(x); }
__device__ __forceinline__ float fsilu(float a) { return a * frcp(1.f + fexp(-a)); }

// async global->LDS, 16B per lane; LDS dest is wave-uniform base + lane*16
__device__ __forceinline__ void gl2lds16(const bf16* g, bf16* l) {
    __builtin_amdgcn_global_load_lds(
        (const __attribute__((address_space(1))) unsigned int*)g,
        (__attribute__((address_space(3))) unsigned int*)l, 16, 0, 0);
}

// ---------- merged init: x->bf16 convert + dt GEMV  AND  weight transposes + rnn copy ----------
// 1D grid: [0,4096) = dtcvt blocks; [4096,4096+1152) = W_in^T tiles;
// [+1152,+1664) = W_out^T tiles; last = rnn copy. Merging removes one dispatch gap.
__global__ __launch_bounds__(256) void k_init(
    const float* __restrict__ x, const float* __restrict__ W_in,
    const float* __restrict__ dt_bias,
    const float* __restrict__ W_out, const float* __restrict__ norm_w,
    const float* __restrict__ rnn,
    bf16* __restrict__ xb, float* __restrict__ dts, float* __restrict__ ssq,
    bf16* __restrict__ W_inbT, bf16* __restrict__ W_outbT, float* __restrict__ outTail)
{
    __shared__ float wcol[D_MODEL];
    __shared__ float tile[32][33];
    int b = blockIdx.x;
    int tid = threadIdx.x;
    if (b < NROWS / 4) {
        // ---- dtcvt part ----
        wcol[tid]       = W_in[(size_t)tid * D_IN_PROJ + 2304];
        wcol[tid + 256] = W_in[(size_t)(tid + 256) * D_IN_PROJ + 2304];
        __syncthreads();
        int row  = b * 4 + (tid >> 6);
        int lane = tid & 63;
        const float* xr = x + (size_t)row * D_MODEL;
        float4 a = *(const float4*)(xr + lane * 8);
        float4 bb = *(const float4*)(xr + lane * 8 + 4);
        union { bf16 o[8]; uint4 u; } pk;
        pk.o[0]=tbf(a.x); pk.o[1]=tbf(a.y); pk.o[2]=tbf(a.z); pk.o[3]=tbf(a.w);
        pk.o[4]=tbf(bb.x); pk.o[5]=tbf(bb.y); pk.o[6]=tbf(bb.z); pk.o[7]=tbf(bb.w);
        *(uint4*)(xb + (size_t)row * D_MODEL + lane * 8) = pk.u;
        const float* wc = wcol + lane * 8;
        float s = a.x*wc[0]+a.y*wc[1]+a.z*wc[2]+a.w*wc[3]
                + bb.x*wc[4]+bb.y*wc[5]+bb.z*wc[6]+bb.w*wc[7];
        #pragma unroll
        for (int off = 32; off; off >>= 1) s += __shfl_xor(s, off);
        if (lane == 0) {
            float raw = s + dt_bias[0];
            dts[row] = raw > 20.f ? raw : log1pf(fexp(raw));
            ssq[row] = 0.f;
        }
        return;
    }
    b -= NROWS / 4;
    if (b == 1152 + 512) {  // rnn passthrough: 8*512 fp32
        #pragma unroll
        for (int i = 0; i < 4; ++i)
            *(float4*)(outTail + (tid + i * 256) * 4) =
                *(const float4*)(rnn + (tid + i * 256) * 4);
        return;
    }
    const float* src; bf16* dst; const float* scale;
    int c0, r0, sstride, C;
    if (b < 1152) {           // W_in[D_MODEL][D_IN_PROJ] -> W_inbT[NPROJ][D_MODEL]
        src = W_in; dst = W_inbT; scale = nullptr;
        c0 = (b % 16) * 32; r0 = (b / 16) * 32; sstride = D_IN_PROJ; C = D_MODEL;
    } else {                  // W_out[D_INNER][D_MODEL] -> W_outbT[D_MODEL][D_INNER], *norm_w
        int bbk = b - 1152;
        src = W_out; dst = W_outbT; scale = norm_w;
        c0 = (bbk % 32) * 32; r0 = (bbk / 32) * 32; sstride = D_MODEL; C = D_INNER;
    }
    int tx = tid & 31, ty = tid >> 5;
    #pragma unroll
    for (int i = 0; i < 32; i += 8) {
        float s = scale ? scale[c0 + ty + i] : 1.f;
        tile[ty + i][tx] = src[(size_t)(c0 + ty + i) * sstride + (r0 + tx)] * s;
    }
    __syncthreads();
    #pragma unroll
    for (int i = 0; i < 32; i += 8)
        dst[(size_t)(r0 + ty + i) * C + (c0 + tx)] = tbf(tile[tx][ty + i]);
}

// ---------- batched NT GEMM, 128x128 tile, BK=64, LDS double-buffer + counted vmcnt ----------
// (round-2 proven config: 256 thr, 4 waves, 64 KiB LDS -> 2 blocks/CU, vmcnt(8) dist-2)
// MODE 0: fp32 out.  MODE 1: bf16 out.
// MODE 2: Y-epilogue — gate with silu(zg), bf16 out, ssq atomics. bm==0, bi=blockIdx.x
//         (chunk-FASTEST grid: the 8 bn-blocks sharing one A2 chunk sit at id stride
//          128 = 0 mod 8 -> same XCD, co-resident -> A2 tile L2-hot, not refetched 8x.)
// MODE 3: fp32 out scaled by rsqrt(ssq[row]/D_INNER + eps). Grid bm-fastest:
//         the 4 readers of each A-panel are {b,b+128,b+256,b+384} -> same XCD,
//         co-resident -> A fetched once. (bn-fastest swap measured -11 us: do not.)
template<int MODE>
__global__ __launch_bounds__(256) void k_bgemm(
    const bf16* __restrict__ A, int lda, size_t sA,
    const bf16* __restrict__ Bt, int ldb, size_t sB,
    void* __restrict__ Cv, int ldc, size_t sC, int K,
    const bf16* __restrict__ zg, float* __restrict__ ssq)
{
    constexpr int BK = 64;
    __shared__ __align__(16) bf16 SM[4 * 8192];   // As0|Bs0|As1|Bs1 = 64 KiB (2 blocks/CU)
    const int tid = threadIdx.x, lane = tid & 63, wave = tid >> 6;
    const int wm = (wave & 1) * 64, wn = (wave >> 1) * 64;
    const int lr = lane & 15, quad = lane >> 4;
    const int rx = lr & 7;
    size_t bm, bn, bi;
    if (MODE == 2)      { bm = 0; bn = (size_t)blockIdx.y * 128; bi = blockIdx.x; }
    else                { bm = (size_t)blockIdx.x * 128; bn = (size_t)blockIdx.y * 128; bi = blockIdx.z; }
    A  += bi * sA;
    Bt += bi * sB;
    const int srow = lane >> 3;
    const int scol = (((lane & 7) ^ srow) << 3);

    f32x4 acc[4][4];
    #pragma unroll
    for (int i = 0; i < 4; ++i)
        #pragma unroll
        for (int j = 0; j < 4; ++j) acc[i][j] = (f32x4){0.f,0.f,0.f,0.f};

    auto stage = [&](bf16* Ad, bf16* Bd, int k0) {
        #pragma unroll
        for (int q = 0; q < 4; ++q) {
            int rg = wave * 32 + q * 8;
            gl2lds16(A  + (bm + rg + srow) * lda + k0 + scol, Ad + rg * BK);
            gl2lds16(Bt + (bn + rg + srow) * ldb + k0 + scol, Bd + rg * BK);
        }
    };

    const int NT = K / BK;
    stage(SM, SM + 8192, 0);                       // tile 0 -> buf0
    if (NT > 1) stage(SM + 16384, SM + 24576, BK); // tile 1 -> buf1

    for (int kt = 0; kt < NT; ++kt) {
        if (kt + 1 < NT) asm volatile("s_waitcnt vmcnt(8)" ::: "memory");
        else             asm volatile("s_waitcnt vmcnt(0)" ::: "memory");
        __builtin_amdgcn_s_barrier();
        __builtin_amdgcn_sched_barrier(0);
        const bf16* As = SM + (kt & 1) * 16384;
        const bf16* Bs = As + 8192;
        #pragma unroll
        for (int ks = 0; ks < BK; ks += 32) {
            const int off = ((((ks >> 3) + quad) ^ rx) << 3);
            short8 af[4], bg[4];
            #pragma unroll
            for (int i = 0; i < 4; ++i)
                af[i] = *(const short8*)(As + (wm + i*16 + lr) * BK + off);
            #pragma unroll
            for (int j = 0; j < 4; ++j)
                bg[j] = *(const short8*)(Bs + (wn + j*16 + lr) * BK + off);
            #pragma unroll
            for (int i = 0; i < 4; ++i)
                #pragma unroll
                for (int j = 0; j < 4; ++j)
                    acc[i][j] = __builtin_amdgcn_mfma_f32_16x16x32_bf16(af[i], bg[j], acc[i][j], 0,0,0);
        }
        __builtin_amdgcn_sched_barrier(0);
        __builtin_amdgcn_s_barrier();
        if (kt + 2 < NT) {
            bf16* An = SM + (kt & 1) * 16384;
            stage(An, An + 8192, (kt + 2) * BK);
        }
    }
    if (MODE <= 1) {
        #pragma unroll
        for (int i = 0; i < 4; ++i)
            #pragma unroll
            for (int j = 0; j < 4; ++j)
                #pragma unroll
                for (int r = 0; r < 4; ++r) {
                    size_t row = bm + wm + i*16 + quad*4 + r;
                    size_t col = bn + wn + j*16 + lr;
                    float v = acc[i][j][r];
                    if (MODE == 0) ((float*)Cv + bi*sC)[row * ldc + col] = v;
                    else           ((bf16*)Cv + bi*sC)[row * ldc + col] = tbf(v);
                }
    } else if (MODE == 2) {
        // stage zg tile (128 rows x 128 cols, XOR-swizzled) into SM, reusing buf0
        const size_t tokbase = bi * CHUNK;
        const bf16* zrow = zg + tokbase * D_INNER + bn;
        __syncthreads();
        #pragma unroll
        for (int q = 0; q < 8; ++q) {
            int r0 = wave * 32 + q * 4;
            int rr = r0 + (lane >> 4);
            int gl = (lane & 15) ^ (rr & 7);
            gl2lds16(zrow + (size_t)rr * D_INNER + gl * 8, SM + r0 * 128);
        }
        __syncthreads();
        float srw[4][4];
        #pragma unroll
        for (int i = 0; i < 4; ++i)
            #pragma unroll
            for (int r = 0; r < 4; ++r) srw[i][r] = 0.f;
        #pragma unroll
        for (int i = 0; i < 4; ++i)
            #pragma unroll
            for (int j = 0; j < 4; ++j)
                #pragma unroll
                for (int r = 0; r < 4; ++r) {
                    int row = wm + i*16 + quad*4 + r;       // 0..127 (bm==0)
                    int col = wn + j*16 + lr;               // 0..127 local
                    int gph = ((col >> 3) ^ (row & 7));
                    float z = fbf(SM[row * 128 + (gph << 3) + (col & 7)]);
                    float g = acc[i][j][r] * z * frcp(1.f + fexp(-z));
                    ((bf16*)Cv + bi*sC)[(size_t)row * ldc + bn + col] = tbf(g);
                    srw[i][r] += g * g;
                }
        #pragma unroll
        for (int i = 0; i < 4; ++i)
            #pragma unroll
            for (int r = 0; r < 4; ++r) {
                float s = srw[i][r];
                s += __shfl_xor(s, 1);
                s += __shfl_xor(s, 2);
                s += __shfl_xor(s, 4);
                s += __shfl_xor(s, 8);
                if (lr == 0)
                    atomicAdd(ssq + tokbase + wm + i*16 + quad*4 + r, s);
            }
    } else {  // MODE 3
        #pragma unroll
        for (int i = 0; i < 4; ++i)
            #pragma unroll
            for (int r = 0; r < 4; ++r) {
                size_t row = bm + wm + i*16 + quad*4 + r;
                float sc = rsqrtf(ssq[row] * (1.f / D_INNER) + EPS_RMS);
                #pragma unroll
                for (int j = 0; j < 4; ++j) {
                    size_t col = bn + wn + j*16 + lr;
                    ((float*)Cv + bi*sC)[row * ldc + col] = acc[i][j][r] * sc;
                }
            }
    }
}

// ---------- GEMM1 with split output: cols<1024 -> zb, else xBCin ----------
// (round-2 exact config — session best 53.3 us. Six schedule variants tried and all
//  lost: 256^2 4-phase x2 (63-64), depth-4 512thr (64), BK=32 x2 (59, 66).
//  The 2-barrier family is barrier-rate-bound: dist-2/BK=64 minimizes NT at 2 blk/CU.)
__global__ __launch_bounds__(256) void k_gemm_in(
    const bf16* __restrict__ A, const bf16* __restrict__ Bt,
    bf16* __restrict__ zb, bf16* __restrict__ xBCin)
{
    constexpr int BK = 64;
    constexpr int K = D_MODEL;
    constexpr int NT = K / BK;                    // 8
    __shared__ __align__(16) bf16 SM[4 * 8192];   // 64 KiB -> 2 blocks/CU
    const int tid = threadIdx.x, lane = tid & 63, wave = tid >> 6;
    const int wm = (wave & 1) * 64, wn = (wave >> 1) * 64;
    const int lr = lane & 15, quad = lane >> 4;
    const int rx = lr & 7;
    const size_t bm = (size_t)blockIdx.x * 128;
    const int bn = blockIdx.y * 128;
    const int srow = lane >> 3;
    const int scol = (((lane & 7) ^ srow) << 3);

    f32x4 acc[4][4];
    #pragma unroll
    for (int i = 0; i < 4; ++i)
        #pragma unroll
        for (int j = 0; j < 4; ++j) acc[i][j] = (f32x4){0.f,0.f,0.f,0.f};

    auto stage = [&](bf16* Ad, bf16* Bd, int k0) {
        #pragma unroll
        for (int q = 0; q < 4; ++q) {
            int rg = wave * 32 + q * 8;
            gl2lds16(A  + (bm + rg + srow) * K + k0 + scol, Ad + rg * BK);
            gl2lds16(Bt + ((size_t)bn + rg + srow) * K + k0 + scol, Bd + rg * BK);
        }
    };

    stage(SM, SM + 8192, 0);
    stage(SM + 16384, SM + 24576, BK);

    for (int kt = 0; kt < NT; ++kt) {
        if (kt + 1 < NT) asm volatile("s_waitcnt vmcnt(8)" ::: "memory");
        else             asm volatile("s_waitcnt vmcnt(0)" ::: "memory");
        __builtin_amdgcn_s_barrier();
        __builtin_amdgcn_sched_barrier(0);
        const bf16* As = SM + (kt & 1) * 16384;
        const bf16* Bs = As + 8192;
        #pragma unroll
        for (int ks = 0; ks < BK; ks += 32) {
            const int off = ((((ks >> 3) + quad) ^ rx) << 3);
            short8 af[4], bg[4];
            #pragma unroll
            for (int i = 0; i < 4; ++i)
                af[i] = *(const short8*)(As + (wm + i*16 + lr) * BK + off);
            #pragma unroll
            for (int j = 0; j < 4; ++j)
                bg[j] = *(const short8*)(Bs + (wn + j*16 + lr) * BK + off);
            #pragma unroll
            for (int i = 0; i < 4; ++i)
                #pragma unroll
                for (int j = 0; j < 4; ++j)
                    acc[i][j] = __builtin_amdgcn_mfma_f32_16x16x32_bf16(af[i], bg[j], acc[i][j], 0,0,0);
        }
        __builtin_amdgcn_sched_barrier(0);
        __builtin_amdgcn_s_barrier();
        if (kt + 2 < NT) {
            bf16* An = SM + (kt & 1) * 16384;
            stage(An, An + 8192, (kt + 2) * BK);
        }
    }
    #pragma unroll
    for (int i = 0; i < 4; ++i)
        #pragma unroll
        for (int j = 0; j < 4; ++j)
            #pragma unroll
            for (int r = 0; r < 4; ++r) {
                size_t row = bm + wm + i*16 + quad*4 + r;
                int col = bn + wn + j*16 + lr;
                float v = acc[i][j][r];
                if (col < D_INNER) zb[row * D_INNER + col] = tbf(v);
                else xBCin[row * CONV_DIM + (col - D_INNER)] = tbf(v);
            }
}

// ---------- per-chunk cumsum of a_t = A*dt, decay factors ----------
__global__ void k_prep(const float* __restrict__ dts, const float* __restrict__ A_log,
                       float* __restrict__ svec, float* __restrict__ wvec,
                       float* __restrict__ esvec, float* __restrict__ Pc)
{
    int chunk = blockIdx.x, t = threadIdx.x;  // 128 threads
    int row = chunk * CHUNK + t;
    float A = -fexp(A_log[0]);
    __shared__ float sh[CHUNK];
    sh[t] = A * dts[row];
    __syncthreads();
    for (int off = 1; off < CHUNK; off <<= 1) {
        float v = (t >= off) ? sh[t - off] : 0.f;
        __syncthreads();
        sh[t] += v;
        __syncthreads();
    }
    float s = sh[t], sL = sh[CHUNK - 1];
    svec[row]  = s;
    wvec[row]  = fexp(sL - s) * dts[row];
    esvec[row] = fexp(s);
    if (t == CHUNK - 1) Pc[chunk] = fexp(sL);
}

// ---------- fused conv(B,C) + G = C@B^T + Sm epilogue + Bw/Cs builds ----------
// grid NCHUNK, 512 threads (was 256: grid=128 uses only half the CUs, so per-block
// speed is the only lever — 512 threads halve the VALU-bound conv + Sm phases).
// Conv: thread = (ch, t-quarter); G-GEMM: 8 waves, 64x32 tiles (acc[4][2]).
__global__ __launch_bounds__(512) void k_ssd_bc(
    const bf16* __restrict__ xBCin, const float* __restrict__ conv_w,
    const float* __restrict__ conv_b, const float* __restrict__ wvec,
    const float* __restrict__ esvec, const float* __restrict__ svec,
    const float* __restrict__ dts, const float* __restrict__ Dp,
    bf16* __restrict__ Bw, bf16* __restrict__ A2)
{
    __shared__ __align__(16) bf16 Ls[131][128];
    __shared__ __align__(16) bf16 Bts[128][136];
    __shared__ __align__(16) bf16 Cts[128][136];
    __shared__ float sv_s[128], dt_s[128], wv_s[128], es_s[128];
    const int chunk = blockIdx.x;
    const int tid = threadIdx.x;
    const bool first = (chunk % CPB) == 0;
    const size_t rowbase = (size_t)chunk * CHUNK;
    if (tid < 128) {
        sv_s[tid] = svec[rowbase + tid];
        dt_s[tid] = dts[rowbase + tid];
        wv_s[tid] = wvec[rowbase + tid];
        es_s[tid] = esvec[rowbase + tid];
    }
    const int ch = tid & 127;
    const int qt = tid >> 7;   // t-quarter (0..3)

    #pragma unroll
    for (int phase = 0; phase < 2; ++phase) {
        const int coff = D_INNER + phase * 128;   // B then C channel base
        __syncthreads();
        for (int i = tid; i < 131 * 16; i += 512) {
            int r = i >> 4, cg = (i & 15) << 3;
            uint4 v = (uint4){0,0,0,0};
            if (!(first && r < 3))
                v = *(const uint4*)(xBCin + (rowbase + r - 3) * CONV_DIM + coff + cg);
            *(uint4*)(&Ls[r][cg]) = v;
        }
        __syncthreads();
        float4 w = *(const float4*)(conv_w + (coff + ch) * 4);
        float bias = conv_b[coff + ch];
        float xv[11];
        #pragma unroll
        for (int i = 0; i < 3; ++i) xv[i + 8] = fbf(Ls[qt * 32 + i][ch]);
        for (int v = 0; v < 4; ++v) {
            int t0 = qt * 32 + v * 8;
            xv[0]=xv[8]; xv[1]=xv[9]; xv[2]=xv[10];
            #pragma unroll
            for (int i = 3; i < 11; ++i) xv[i] = fbf(Ls[t0 + i][ch]);
            float o[8];
            #pragma unroll
            for (int j = 0; j < 8; ++j) {
                float a = bias + w.x*xv[j] + w.y*xv[j+1] + w.z*xv[j+2] + w.w*xv[j+3];
                o[j] = fsilu(a);
            }
            if (phase == 0) {
                union { bf16 ob[8]; uint4 u; } pk;
                #pragma unroll
                for (int j = 0; j < 8; ++j) {
                    Bts[t0 + j][ch] = tbf(o[j]);
                    pk.ob[j] = tbf(o[j] * wv_s[t0 + j]);
                }
                *(uint4*)(Bw + (size_t)chunk*(D_STATE*CHUNK) + (size_t)ch*CHUNK + t0) = pk.u;
            } else {
                #pragma unroll
                for (int j = 0; j < 8; ++j) {
                    Cts[t0 + j][ch] = tbf(o[j]);
                    A2[(size_t)chunk*(CHUNK*256) + (size_t)(t0+j)*256 + 128 + ch] =
                        tbf(o[j] * es_s[t0 + j]);
                }
            }
        }
    }
    __syncthreads();
    // G = C @ B^T from LDS (K=128), 8 waves: 64x32 wave tiles. Sm epilogue -> A2[:, 0:128]
    const int lane = tid & 63, wave = tid >> 6;
    const int wm = (wave & 1) * 64, wn = (wave >> 1) * 32;
    const int lr = lane & 15, quad = lane >> 4;
    f32x4 acc[4][2];
    #pragma unroll
    for (int i = 0; i < 4; ++i)
        #pragma unroll
        for (int j = 0; j < 2; ++j) acc[i][j] = (f32x4){0.f,0.f,0.f,0.f};
    #pragma unroll
    for (int ks = 0; ks < 128; ks += 32) {
        short8 af[4], bg[2];
        #pragma unroll
        for (int i = 0; i < 4; ++i)
            af[i] = *(const short8*)(&Cts[wm + i*16 + lr][ks + quad*8]);
        #pragma unroll
        for (int j = 0; j < 2; ++j)
            bg[j] = *(const short8*)(&Bts[wn + j*16 + lr][ks + quad*8]);
        #pragma unroll
        for (int i = 0; i < 4; ++i)
            #pragma unroll
            for (int j = 0; j < 2; ++j)
                acc[i][j] = __builtin_amdgcn_mfma_f32_16x16x32_bf16(af[i], bg[j], acc[i][j], 0,0,0);
    }
    const float D0 = Dp[0];
    #pragma unroll
    for (int i = 0; i < 4; ++i)
        #pragma unroll
        for (int j = 0; j < 2; ++j)
            #pragma unroll
            for (int r = 0; r < 4; ++r) {
                int t = wm + i*16 + quad*4 + r;
                int u = wn + j*16 + lr;
                float o = 0.f;
                if (u <= t) {
                    o = acc[i][j][r] * fexp(sv_s[t] - sv_s[u]) * dt_s[u];
                    if (u == t) o += D0;
                }
                A2[(size_t)chunk*(CHUNK*256) + (size_t)t*256 + u] = tbf(o);
            }
}

// ---------- fused conv(x) -> Xt (B2 + swizzled LDS) + dH = Xt @ Bw^T ----------
// grid (NCHUNK, 8), 256 threads — chunk-FASTEST so the 8 p0-blocks sharing one
// chunk's Bw tile sit at id stride 128 = 0 mod 8 -> same XCD, co-resident.
__global__ __launch_bounds__(256) void k_conv_xdh(
    const bf16* __restrict__ xBCin, const float* __restrict__ conv_w,
    const float* __restrict__ conv_b, const bf16* __restrict__ Bw,
    bf16* __restrict__ B2, bf16* __restrict__ dH)
{
    __shared__ __align__(16) bf16 Ls[131][128];
    __shared__ __align__(16) bf16 XsF[128 * 128];  // [p][t], t-groups XOR-swizzled by p&7
    const int chunk = blockIdx.x;
    const int p0 = blockIdx.y * 128;
    const int tid = threadIdx.x;
    const bool first = (chunk % CPB) == 0;
    const size_t rowbase = (size_t)chunk * CHUNK;
    for (int i = tid; i < 131 * 16; i += 256) {
        int r = i >> 4, cg = (i & 15) << 3;
        uint4 v = (uint4){0,0,0,0};
        if (!(first && r < 3))
            v = *(const uint4*)(xBCin + (rowbase + r - 3) * CONV_DIM + p0 + cg);
        *(uint4*)(&Ls[r][cg]) = v;
    }
    __syncthreads();
    const int p = tid & 127;
    const int half = tid >> 7;
    const int ch = p0 + p;
    float4 w = *(const float4*)(conv_w + ch * 4);
    float bias = conv_b[ch];
    bf16* outrow = B2 + (size_t)chunk * (D_INNER * 256) + (size_t)ch * 256;
    float xv[11];
    #pragma unroll
    for (int i = 0; i < 3; ++i) xv[i + 8] = fbf(Ls[half * 64 + i][p]);
    for (int v = 0; v < 8; ++v) {
        int t0 = half * 64 + v * 8;
        xv[0]=xv[8]; xv[1]=xv[9]; xv[2]=xv[10];
        #pragma unroll
        for (int i = 3; i < 11; ++i) xv[i] = fbf(Ls[t0 + i][p]);
        union { bf16 o[8]; uint4 u; } pk;
        #pragma unroll
        for (int j = 0; j < 8; ++j) {
            float a = bias + w.x*xv[j] + w.y*xv[j+1] + w.z*xv[j+2] + w.w*xv[j+3];
            pk.o[j] = tbf(fsilu(a));
        }
        *(uint4*)(outrow + t0) = pk.u;
        *(uint4*)(&XsF[p * 128 + ((((t0 >> 3) ^ (p & 7))) << 3)]) = pk.u;
    }
    __syncthreads();
    // dH[p][n] = sum_t Xs[p][t] * Bw[n][t]  (K=128; B-frags straight from global)
    const int lane = tid & 63, wave = tid >> 6;
    const int wm = (wave & 1) * 64, wn = (wave >> 1) * 64;
    const int lr = lane & 15, quad = lane >> 4;
    const bf16* bwc = Bw + (size_t)chunk * (D_STATE * CHUNK);
    f32x4 acc[4][4];
    #pragma unroll
    for (int i = 0; i < 4; ++i)
        #pragma unroll
        for (int j = 0; j < 4; ++j) acc[i][j] = (f32x4){0.f,0.f,0.f,0.f};
    #pragma unroll
    for (int ks = 0; ks < 128; ks += 32) {
        short8 af[4], bg[4];
        #pragma unroll
        for (int j = 0; j < 4; ++j)
            bg[j] = *(const short8*)(bwc + (size_t)(wn + j*16 + lr) * CHUNK + ks + quad*8);
        #pragma unroll
        for (int i = 0; i < 4; ++i)
            af[i] = *(const short8*)(&XsF[(wm + i*16 + lr) * 128 +
                                          (((((ks >> 3) + quad) ^ (lr & 7))) << 3)]);
        #pragma unroll
        for (int i = 0; i < 4; ++i)
            #pragma unroll
            for (int j = 0; j < 4; ++j)
                acc[i][j] = __builtin_amdgcn_mfma_f32_16x16x32_bf16(af[i], bg[j], acc[i][j], 0,0,0);
    }
    #pragma unroll
    for (int i = 0; i < 4; ++i)
        #pragma unroll
        for (int j = 0; j < 4; ++j)
            #pragma unroll
            for (int r = 0; r < 4; ++r) {
                int pr = p0 + wm + i*16 + quad*4 + r;
                int n  = wn + j*16 + lr;
                dH[(size_t)chunk*(D_INNER*D_STATE) + (size_t)pr*D_STATE + n] = tbf(acc[i][j][r]);
            }
}

// ---------- sequential carry over 16 chunks/batch, fully vectorized ----------
__global__ __launch_bounds__(256) void k_carry(
    const bf16* __restrict__ dH, const float* __restrict__ Pc, bf16* __restrict__ B2)
{
    int idx = blockIdx.x * 256 + threadIdx.x;   // 0..16383
    int b = blockIdx.y;
    int p = idx >> 4, ng = (idx & 15) << 3;
    uint4 v[CPB];
    float pc[CPB];
    #pragma unroll
    for (int c = 0; c < CPB; ++c)
        v[c] = *(const uint4*)(dH + (size_t)(b*CPB + c)*(D_INNER*D_STATE) + (size_t)p*D_STATE + ng);
    #pragma unroll
    for (int c = 0; c < CPB; ++c) pc[c] = Pc[b*CPB + c];
    float h[8] = {0,0,0,0,0,0,0,0};
    #pragma unroll
    for (int c = 0; c < CPB; ++c) {
        union { bf16 o[8]; uint4 u; } pk;
        #pragma unroll
        for (int k = 0; k < 8; ++k) pk.o[k] = tbf(h[k]);
        *(uint4*)(B2 + (size_t)(b*CPB + c)*(D_INNER*256) + (size_t)p*256 + 128 + ng) = pk.u;
        const bf16* vb = (const bf16*)&v[c];
        #pragma unroll
        for (int k = 0; k < 8; ++k) h[k] = pc[c]*h[k] + fbf(vb[k]);
    }
}

extern "C" void kernel_launch(void* const* d_in, const int* in_sizes, int n_in,
                              void* d_out, int out_size, void* d_ws, size_t ws_size,
                              hipStream_t stream)
{
    const float* x       = (const float*)d_in[0];
    const float* rnn     = (const float*)d_in[1];
    const float* W_in    = (const float*)d_in[2];
    const float* conv_w  = (const float*)d_in[3];
    const float* conv_b  = (const float*)d_in[4];
    const float* dt_bias = (const float*)d_in[5];
    const float* A_log   = (const float*)d_in[6];
    const float* Dp      = (const float*)d_in[7];
    const float* norm_w  = (const float*)d_in[8];
    const float* W_out   = (const float*)d_in[9];
    float* out = (float*)d_out;

    char* ws = (char*)d_ws;
    size_t off = 0;
    auto alloc = [&](size_t bytes) { void* p = ws + off; off += (bytes + 255) & ~255ULL; return p; };

    // ---- persistent ----
    bf16*  W_inbT  = (bf16*) alloc((size_t)NPROJ * D_MODEL * 2);        // 2.36M
    bf16*  W_outbT = (bf16*) alloc((size_t)D_MODEL * D_INNER * 2);      // 1.05M (norm_w folded)
    float* dts     = (float*)alloc((size_t)NROWS * 4);
    float* svec    = (float*)alloc((size_t)NROWS * 4);
    float* wvec    = (float*)alloc((size_t)NROWS * 4);
    float* esvec   = (float*)alloc((size_t)NROWS * 4);
    float* Pc      = (float*)alloc((size_t)NCHUNK * 4);
    float* ssq     = (float*)alloc((size_t)NROWS * 4);                  // RMS sumsq accum
    bf16*  zb      = (bf16*) alloc((size_t)NROWS * D_INNER * 2);        // 33.5M
    bf16*  A2      = (bf16*) alloc((size_t)NCHUNK * CHUNK * 256 * 2);   // 8.4M  [Sm | Cs]
    bf16*  B2      = (bf16*) alloc((size_t)NCHUNK * D_INNER * 256 * 2); // 67.1M [Xt | Hprev]
    bf16*  Bw      = (bf16*) alloc((size_t)NCHUNK * D_STATE * CHUNK * 2); // 4.2M
    // ---- aliased region A (50.3M): xb[0:16.8]+dH[16.8:50.3], later ybf[0:33.5] ----
    char* RA = (char*)alloc((size_t)NROWS * D_MODEL * 2 + (size_t)NROWS * D_INNER * 2);
    bf16*  xb   = (bf16*)RA;                                   // [init -> GEMM1]
    bf16*  dH   = (bf16*)(RA + (size_t)NROWS * D_MODEL * 2);   // [conv_xdh -> carry]
    bf16*  ybf  = (bf16*)RA;                                   // [Y-GEMM -> GEMM2]
    // ---- region B: xBCin [GEMM1 -> convs] ----
    bf16*  xBCin = (bf16*)alloc((size_t)NROWS * CONV_DIM * 2); // 41.9M
    // total ~200 MB

    // 1. merged init (convert + dt GEMV + ssq zeroing + transposes + rnn copy); prep
    k_init<<<NROWS/4 + 1152 + 512 + 1, 256, 0, stream>>>(
        x, W_in, dt_bias, W_out, norm_w, rnn,
        xb, dts, ssq, W_inbT, W_outbT, out + (size_t)NROWS * D_MODEL);
    k_prep<<<NCHUNK, CHUNK, 0, stream>>>(dts, A_log, svec, wvec, esvec, Pc);

    // 2. in-projection GEMM with split output (round-2 proven config)
    k_gemm_in<<<dim3(NROWS/128, NPROJ/128), 256, 0, stream>>>(xb, W_inbT, zb, xBCin);

    // 3. fused conv(B,C) + G-GEMM + Sm -> A2, Bw (512 threads: grid=128 is CU-limited,
    //    so halving per-thread VALU work is the only lever)
    k_ssd_bc<<<NCHUNK, 512, 0, stream>>>(xBCin, conv_w, conv_b, wvec, esvec,
                                         svec, dts, Dp, Bw, A2);

    // 4. fused conv(x) -> Xt(B2) + dH-GEMM (chunk-fastest grid: Bw shared on one XCD)
    k_conv_xdh<<<dim3(NCHUNK, 8), 256, 0, stream>>>(xBCin, conv_w, conv_b, Bw, B2, dH);

    // 5. carry states -> Hprev region of B2
    k_carry<<<dim3(64, BATCH), 256, 0, stream>>>(dH, Pc, B2);

    // 6. Y = [Sm|Cs] @ [Xt|Hprev]^T (K=256) -> gated bf16 ybf + row sumsq atomics
    //    (chunk-fastest grid: the 8 bn-blocks sharing one A2 chunk land on one XCD)
    k_bgemm<2><<<dim3(NCHUNK, D_INNER/128, 1), 256, 0, stream>>>(
        A2, 256, (size_t)CHUNK*256,
        B2, 256, (size_t)D_INNER*256,
        ybf, D_INNER, (size_t)CHUNK*D_INNER, 256, zb, ssq);

    // 7. out-projection GEMM with RMS post-scale epilogue -> d_out (bm-fastest grid)
    k_bgemm<3><<<dim3(NROWS/128, D_MODEL/128, 1), 256, 0, stream>>>(
        ybf, D_INNER, 0, W_outbT, D_INNER, 0, out, D_MODEL, 0, D_INNER,
        nullptr, ssq);
}